// Round 1
// 214.350 us; speedup vs baseline: 1.0432x; 1.0432x over previous
//
#include <hip/hip_runtime.h>
#include <hip/hip_bf16.h>
#include <stdint.h>
#include <math.h>

// Problem constants
#define D_MODEL 1024
#define NHEAD   16
#define DHEAD   64
#define BATCH   2
#define SEQ     2048
#define M_TOK   (BATCH * SEQ)   // 4096 tokens

// Q pre-scale: 1/sqrt(DHEAD) * log2(e), folded into the Q projection so the
// QK^T MFMA result is directly the exp2 argument.
#define QSCALE 0.18033688011112042f

typedef __attribute__((ext_vector_type(8))) short   short8;
typedef __attribute__((ext_vector_type(8))) __bf16  bf16x8;
typedef __attribute__((ext_vector_type(4))) float   f32x4;

__device__ inline short f2bf(float f) {           // RNE
  unsigned int u = __builtin_bit_cast(unsigned int, f);
  unsigned int r = (u + 0x7FFFu + ((u >> 16) & 1u)) >> 16;
  return (short)(unsigned short)r;
}
__device__ inline short f2bf_fast(float f) {      // round-nearest (ties away), 2 ops
  unsigned int u = __builtin_bit_cast(unsigned int, f);
  return (short)(unsigned short)((u + 0x8000u) >> 16);
}

// async global -> LDS, 16B per lane. LDS dest must be wave-uniform base + lane*16.
__device__ inline void gl_lds16(const void* g, void* l) {
  __builtin_amdgcn_global_load_lds((__attribute__((address_space(1))) void*)(g),
                                   (__attribute__((address_space(3))) void*)(l),
                                   16, 0, 0);
}

__device__ inline bf16x8 lds_frag(const short* p) {
  return *(const bf16x8*)(p);
}
// 8-byte-aligned fragment load (two b64 reads) for the 68-stride P slab
__device__ inline bf16x8 lds_frag64(const short* p) {
  union { bf16x8 v; short4 h[2]; } u;
  u.h[0] = *(const short4*)(p);
  u.h[1] = *(const short4*)(p + 4);
  return u.v;
}

// ---------------------------------------------------------------------------
// Prep kernel (fused): z=0..3 -> transpose+convert weight matrix z
// (W[k][n] fp32 -> Wt[n][k] bf16); z=4 -> convert x fp32 -> bf16.
// Grid (16,16,5), 256 threads. One launch instead of two.
// ---------------------------------------------------------------------------
__global__ __launch_bounds__(256) void prep(const float* __restrict__ x,
                                            short* __restrict__ xb,
                                            const float* __restrict__ w0,
                                            const float* __restrict__ w1,
                                            const float* __restrict__ w2,
                                            const float* __restrict__ w3,
                                            short* __restrict__ out) {
  const int t = threadIdx.x;
  if (blockIdx.z == 4) {
    // convert x: 256 blocks (by*16+bx), 16384 elems each
    size_t base = ((size_t)blockIdx.y * 16 + blockIdx.x) * 16384;
    const float* in = x + base;
    short* o = xb + base;
#pragma unroll
    for (int i = 0; i < 16; ++i) {
      f32x4 v = *(const f32x4*)(in + (size_t)t * 4 + i * 1024);
      short4 s4;
      s4.x = f2bf(v[0]); s4.y = f2bf(v[1]); s4.z = f2bf(v[2]); s4.w = f2bf(v[3]);
      *(short4*)(o + (size_t)t * 4 + i * 1024) = s4;
    }
    return;
  }
  __shared__ short tile[64][72];
  const float* W = blockIdx.z == 0 ? w0 : blockIdx.z == 1 ? w1 : blockIdx.z == 2 ? w2 : w3;
  short* O = out + (size_t)blockIdx.z * (D_MODEL * (size_t)D_MODEL);
  int n0 = blockIdx.x * 64, k0 = blockIdx.y * 64;
#pragma unroll
  for (int i = 0; i < 16; ++i) {
    int idx = t + 256 * i;
    int r = idx >> 6, c = idx & 63;
    tile[r][c] = f2bf(W[(size_t)(k0 + r) * D_MODEL + n0 + c]);
  }
  __syncthreads();
#pragma unroll
  for (int i = 0; i < 16; ++i) {
    int idx = t + 256 * i;
    int r = idx >> 6, c = idx & 63;
    O[(size_t)(n0 + r) * D_MODEL + k0 + c] = tile[c][r];
  }
}

// ---------------------------------------------------------------------------
// GEMM: out[m][n] = A[m][k] * Bt[n][k]^T + bias[n]  (bf16 in, fp32 acc)
// 128xTN tile, BK=64, 256 threads (4 waves, 64x(TN/2) per wave).
// LDS XOR-chunk swizzled. TN=128 for QKV (768 blocks), TN=64 for the output
// projection (512 blocks = 2/CU). [R8 best-measured configuration]
// QKV launch (VT=true): z=0 -> Q scaled by QSCALE; z=2 -> V written transposed
// with MASKED KEY ROWS ZEROED (pm[b][s]==1 -> 0).
// ---------------------------------------------------------------------------
template <bool OUTF32, bool VT, int TN>
__global__ __launch_bounds__(256) void gemm128(const short* __restrict__ A,
                                               const short* __restrict__ Bt_base,
                                               const float* __restrict__ b0,
                                               const float* __restrict__ b1,
                                               const float* __restrict__ b2,
                                               void* __restrict__ out_base,
                                               short* __restrict__ vt,
                                               const int* __restrict__ pm) {
  constexpr int NI = TN / 32;      // per-wave n-subtiles (4 or 2)
  const int z = blockIdx.z;
  const short* Bt   = Bt_base + (size_t)z * (D_MODEL * (size_t)D_MODEL);
  const float* bias = (z == 0) ? b0 : (z == 1) ? b1 : b2;

  __shared__ short As[128 * 64];   // [row][k] 64-wide rows, swizzled
  __shared__ short Bs[TN * 64];    // [n][k], swizzled

  const int t = threadIdx.x;
  const int lane = t & 63;
  const int wid = t >> 6;
  const int wm = (wid >> 1) * 64, wn = (wid & 1) * (TN / 2);
  const int m0 = blockIdx.x * 128, n0 = blockIdx.y * TN;
  const int cl = lane & 15, q = lane >> 4;
  const int sw = cl & 7;

  f32x4 acc[4][NI];
#pragma unroll
  for (int i = 0; i < 4; ++i)
#pragma unroll
    for (int j = 0; j < NI; ++j) acc[i][j] = 0.0f;

  for (int k0 = 0; k0 < D_MODEL; k0 += 64) {
    __syncthreads();
#pragma unroll
    for (int i = 0; i < 4; ++i) {   // A: 1024 chunks
      int c = t + 256 * i;
      int row = c >> 3, cp = c & 7;
      int col = ((cp ^ (row & 7)) * 8);
      gl_lds16(A + (size_t)(m0 + row) * D_MODEL + k0 + col, (void*)(As + c * 8));
    }
#pragma unroll
    for (int i = 0; i < NI; ++i) {  // B: TN*8 chunks
      int c = t + 256 * i;
      int row = c >> 3, cp = c & 7;
      int col = ((cp ^ (row & 7)) * 8);
      gl_lds16(Bt + (size_t)(n0 + row) * D_MODEL + k0 + col, (void*)(Bs + c * 8));
    }
    __syncthreads();

    bf16x8 af[4][2], bfr[NI][2];
#pragma unroll
    for (int mi = 0; mi < 4; ++mi) {
      af[mi][0] = lds_frag(As + (wm + mi * 16 + cl) * 64 + (q ^ sw) * 8);
      af[mi][1] = lds_frag(As + (wm + mi * 16 + cl) * 64 + ((4 + q) ^ sw) * 8);
    }
#pragma unroll
    for (int ni = 0; ni < NI; ++ni) {
      bfr[ni][0] = lds_frag(Bs + (wn + ni * 16 + cl) * 64 + (q ^ sw) * 8);
      bfr[ni][1] = lds_frag(Bs + (wn + ni * 16 + cl) * 64 + ((4 + q) ^ sw) * 8);
    }
#pragma unroll
    for (int mi = 0; mi < 4; ++mi)
#pragma unroll
      for (int ni = 0; ni < NI; ++ni) {
        acc[mi][ni] = __builtin_amdgcn_mfma_f32_16x16x32_bf16(af[mi][0], bfr[ni][0], acc[mi][ni], 0, 0, 0);
        acc[mi][ni] = __builtin_amdgcn_mfma_f32_16x16x32_bf16(af[mi][1], bfr[ni][1], acc[mi][ni], 0, 0, 0);
      }
  }

  // Epilogue: C/D layout col=lane&15, row=(lane>>4)*4+reg
  const float oscale = (VT && z == 0) ? QSCALE : 1.0f;
  int4 mm[4];
  if (VT && z == 2) {
#pragma unroll
    for (int mi = 0; mi < 4; ++mi) {
      int rbase = m0 + wm + mi * 16 + q * 4;
      mm[mi] = *(const int4*)(pm + (size_t)(rbase >> 11) * SEQ + (rbase & (SEQ - 1)));
    }
  }
#pragma unroll
  for (int ni = 0; ni < NI; ++ni) {
    int col = n0 + wn + ni * 16 + cl;
    float bv = bias[col];
#pragma unroll
    for (int mi = 0; mi < 4; ++mi) {
      int rbase = m0 + wm + mi * 16 + q * 4;
      if (VT && z == 2) {
        short4 o4;
        o4.x = (mm[mi].x == 1) ? (short)0 : f2bf_fast(acc[mi][ni][0] + bv);
        o4.y = (mm[mi].y == 1) ? (short)0 : f2bf_fast(acc[mi][ni][1] + bv);
        o4.z = (mm[mi].z == 1) ? (short)0 : f2bf_fast(acc[mi][ni][2] + bv);
        o4.w = (mm[mi].w == 1) ? (short)0 : f2bf_fast(acc[mi][ni][3] + bv);
        int btok = rbase >> 11;           // token block -> batch
        int s    = rbase & (SEQ - 1);
        *(short4*)(vt + (size_t)btok * ((size_t)D_MODEL * SEQ) + (size_t)col * SEQ + s) = o4;
      } else {
#pragma unroll
        for (int r = 0; r < 4; ++r) {
          float v = (acc[mi][ni][r] + bv) * oscale;
          size_t idx = (size_t)(rbase + r) * D_MODEL + col;
          if (OUTF32) {
            ((float*)out_base)[idx] = v;
          } else {
            short* out = (short*)out_base + (size_t)z * ((size_t)M_TOK * D_MODEL);
            out[idx] = f2bf_fast(v);
          }
        }
      }
    }
  }
}

// ---------------------------------------------------------------------------
// Flash attention v5: 512 threads / 8 waves, in-block KV-split.
// Counters at v4 showed Occupancy 19% (grid 512 blocks = 2/CU at 4 waves),
// VALUBusy 51%, MfmaUtil 19.5% -> latency-bound at 2 waves/SIMD.
// The fixed-max softmax makes O and l PURE SUMS over keys, so the KV range
// splits linearly: waves pair up as (row-group wg = wid>>1, kv-half = wid&1).
// Each wave: 32 q-rows x 16 kv-tiles (per-wave per-tile work identical to v4,
// so frag reads / exp count / MFMA count are NOT duplicated; HBM traffic
// unchanged). 16 waves/CU = 4/SIMD. One-time LDS combine merges kv-halves.
// ---------------------------------------------------------------------------
__global__ __launch_bounds__(512) void attn_flash(const short* __restrict__ Q,
                                                  const short* __restrict__ K,
                                                  const short* __restrict__ Vt,
                                                  const int*   __restrict__ mask,
                                                  short* __restrict__ ctx) {
  const int qb = blockIdx.x;   // 0..15
  const int h  = blockIdx.y;   // 0..15
  const int b  = blockIdx.z;   // 0..1

  // union: Q stage (8192 shorts) / P slabs 8 x 32x68 (17408 shorts)
  //        / epilogue redO (4*64*32 f32 = 32768B)
  __shared__ __align__(16) short QPs[17408];
  __shared__ __align__(16) short Ks[2 * 64 * 64];   // [half][key][d] swizzled; epi: redL
  __shared__ __align__(16) short Vts[2 * 64 * 64];  // [half][d][key] swizzled
  __shared__ __align__(16) short Us[2 * 64];        // u[key] = mask?0:1 per half

  const int t = threadIdx.x;
  const int lane = t & 63;
  const int wid = t >> 6;           // 0..7
  const int wg  = wid >> 1;         // row-group 0..3 (32 q-rows each)
  const int kvh = wid & 1;          // kv half: keys [kvh*1024, kvh*1024+1024)
  const int cl = lane & 15, q = lane >> 4;
  const int sw = cl & 7;

  const size_t rowQ0 = (size_t)b * SEQ + (size_t)qb * 128;
  const size_t rowK0 = (size_t)b * SEQ;
  const size_t vbase = ((size_t)b * D_MODEL + h * DHEAD) * SEQ;

  // stage Q tile (128 rows x 64 d), swizzled, into the union region
#pragma unroll
  for (int i = 0; i < 2; ++i) {
    int c = t + 512 * i;
    int row = c >> 3, cp = c & 7;
    gl_lds16(Q + (rowQ0 + row) * D_MODEL + h * DHEAD + ((cp ^ (row & 7)) * 8),
             (void*)(QPs + c * 8));
  }
  __syncthreads();

  // Register-resident Q fragments: wave owns rows [32*wg, 32*wg+32)
  bf16x8 qf[2][2];
#pragma unroll
  for (int rb = 0; rb < 2; ++rb) {
    int row = wg * 32 + rb * 16 + cl;
    qf[rb][0] = lds_frag(QPs + row * 64 + (q ^ sw) * 8);
    qf[rb][1] = lds_frag(QPs + row * 64 + ((4 + q) ^ sw) * 8);
  }
  short* Psw = QPs + wid * (32 * 68);   // wave-private P slab, stride 68
  const short* Kp = Ks  + kvh * 4096;
  const short* Vp = Vts + kvh * 4096;
  const short* Up = Us  + kvh * 64;

  f32x4 lacc[2], oacc[2][4];
#pragma unroll
  for (int rb = 0; rb < 2; ++rb) {
    lacc[rb] = 0.0f;
#pragma unroll
    for (int dj = 0; dj < 4; ++dj) oacc[rb][dj] = 0.0f;
  }

  for (int s0 = 0; s0 < 1024; s0 += 64) {
    __syncthreads();   // prior readers of Ks/Vts/Us done; orders qf reads too

    // stage BOTH kv-halves' K tile (64 keys x 64 d) and Vt tile (64 d x 64
    // keys), swizzled. 1 chunk per thread per tile.
    {
      int row = t >> 3, cp = t & 7;
      int col = (cp ^ (row & 7)) * 8;
      gl_lds16(K + (rowK0 + s0 + row) * D_MODEL + h * DHEAD + col,
               (void*)(Ks + t * 8));
      gl_lds16(K + (rowK0 + 1024 + s0 + row) * D_MODEL + h * DHEAD + col,
               (void*)(Ks + 4096 + t * 8));
      gl_lds16(Vt + vbase + (size_t)row * SEQ + s0 + col,
               (void*)(Vts + t * 8));
      gl_lds16(Vt + vbase + (size_t)row * SEQ + 1024 + s0 + col,
               (void*)(Vts + 4096 + t * 8));
    }
    if (t < 128)
      Us[t] = (mask[(size_t)b * SEQ + (t >> 6) * 1024 + s0 + (t & 63)] == 1)
                  ? (short)0 : (short)0x3F80;
    __syncthreads();

    // S~ = Qs K^T  (C-layout: row = q*4+r, col = j*16+cl); K frags feed both rb
    f32x4 s[2][4];
#pragma unroll
    for (int j = 0; j < 4; ++j) {
      bf16x8 kf0 = lds_frag(Kp + (j * 16 + cl) * 64 + (q ^ sw) * 8);
      bf16x8 kf1 = lds_frag(Kp + (j * 16 + cl) * 64 + ((4 + q) ^ sw) * 8);
#pragma unroll
      for (int rb = 0; rb < 2; ++rb) {
        f32x4 sa = 0.0f;
        sa = __builtin_amdgcn_mfma_f32_16x16x32_bf16(qf[rb][0], kf0, sa, 0, 0, 0);
        sa = __builtin_amdgcn_mfma_f32_16x16x32_bf16(qf[rb][1], kf1, sa, 0, 0, 0);
        s[rb][j] = sa;
      }
    }

    // p = exp2(s): no mask, no scalar l. Write P slab.
#pragma unroll
    for (int rb = 0; rb < 2; ++rb)
#pragma unroll
      for (int j = 0; j < 4; ++j)
#pragma unroll
        for (int r = 0; r < 4; ++r)
          Psw[(rb * 16 + q * 4 + r) * 68 + j * 16 + cl] = f2bf_fast(exp2f(s[rb][j][r]));

    // Pin order: P-slab stores must not be reordered after the pf loads
    // (cross-lane RAW through LDS; per-thread alias analysis can't see it).
    asm volatile("" ::: "memory");

    // O += P V ; l += P u  (V/u frags feed both rb)
    bf16x8 pf[2][2];
#pragma unroll
    for (int rb = 0; rb < 2; ++rb) {
      pf[rb][0] = lds_frag64(Psw + (rb * 16 + cl) * 68 + q * 8);
      pf[rb][1] = lds_frag64(Psw + (rb * 16 + cl) * 68 + 32 + q * 8);
    }
    bf16x8 uf0 = lds_frag(Up + q * 8);          // broadcast across cl: conflict-free
    bf16x8 uf1 = lds_frag(Up + 32 + q * 8);
#pragma unroll
    for (int dj = 0; dj < 4; ++dj) {
      bf16x8 vf0 = lds_frag(Vp + (dj * 16 + cl) * 64 + (q ^ sw) * 8);
      bf16x8 vf1 = lds_frag(Vp + (dj * 16 + cl) * 64 + ((4 + q) ^ sw) * 8);
#pragma unroll
      for (int rb = 0; rb < 2; ++rb) {
        oacc[rb][dj] = __builtin_amdgcn_mfma_f32_16x16x32_bf16(pf[rb][0], vf0, oacc[rb][dj], 0, 0, 0);
        oacc[rb][dj] = __builtin_amdgcn_mfma_f32_16x16x32_bf16(pf[rb][1], vf1, oacc[rb][dj], 0, 0, 0);
      }
    }
#pragma unroll
    for (int rb = 0; rb < 2; ++rb) {
      lacc[rb] = __builtin_amdgcn_mfma_f32_16x16x32_bf16(pf[rb][0], uf0, lacc[rb], 0, 0, 0);
      lacc[rb] = __builtin_amdgcn_mfma_f32_16x16x32_bf16(pf[rb][1], uf1, lacc[rb], 0, 0, 0);
    }
  }

  // ---- combine kv-halves through LDS (O,l are linear in the key axis) ----
  __syncthreads();                    // all compute reads of LDS done
  float* redO = (float*)QPs;          // 32768B needed <= 34816B
  float* redL = (float*)Ks;           // 8192B needed <= 16384B
  const int rbase = (wg * 64 + lane) * 32;
  const int lbase = (wg * 64 + lane) * 8;
  if (kvh) {
#pragma unroll
    for (int rb = 0; rb < 2; ++rb) {
#pragma unroll
      for (int dj = 0; dj < 4; ++dj) {
        int qi = (rb * 4 + dj) ^ (lane & 7);   // XOR-swizzle: spread banks
        *(f32x4*)(redO + rbase + qi * 4) = oacc[rb][dj];
      }
      *(f32x4*)(redL + lbase + rb * 4) = lacc[rb];
    }
  }
  __syncthreads();
  if (kvh) return;
#pragma unroll
  for (int rb = 0; rb < 2; ++rb) {
    lacc[rb] += *(const f32x4*)(redL + lbase + rb * 4);
#pragma unroll
    for (int dj = 0; dj < 4; ++dj) {
      int qi = (rb * 4 + dj) ^ (lane & 7);
      oacc[rb][dj] += *(const f32x4*)(redO + rbase + qi * 4);
    }
  }

  // finalize: l = lacc (full row-sum, same C-layout rows), O/l, store
#pragma unroll
  for (int rb = 0; rb < 2; ++rb)
#pragma unroll
    for (int dj = 0; dj < 4; ++dj)
#pragma unroll
      for (int r = 0; r < 4; ++r) {
        float lv = lacc[rb][r];
        float o = (lv > 0.0f) ? oacc[rb][dj][r] / lv : 0.0f;
        size_t row = rowQ0 + wg * 32 + rb * 16 + q * 4 + r;
        ctx[row * D_MODEL + h * DHEAD + dj * 16 + cl] = f2bf(o);
      }
}

// ---------------------------------------------------------------------------
extern "C" void kernel_launch(void* const* d_in, const int* in_sizes, int n_in,
                              void* d_out, int out_size, void* d_ws, size_t ws_size,
                              hipStream_t stream) {
  (void)in_sizes; (void)n_in; (void)out_size; (void)ws_size;

  const float* x  = (const float*)d_in[0];
  const int*   pm = (const int*)  d_in[1];
  const float* Wq = (const float*)d_in[2];
  const float* bq = (const float*)d_in[3];
  const float* Wk = (const float*)d_in[4];
  const float* bk = (const float*)d_in[5];
  const float* Wv = (const float*)d_in[6];
  const float* bv = (const float*)d_in[7];
  const float* Wo = (const float*)d_in[8];
  const float* bo = (const float*)d_in[9];

  const size_t WMAT = (size_t)D_MODEL * D_MODEL;   // 1M elems
  const size_t TOKD = (size_t)M_TOK * D_MODEL;     // 4M elems

  short* base = (short*)d_ws;
  short* Wt = base;              // 4 transposed bf16 weights: 8 MB
  short* xb = base + 4 * WMAT;   // bf16 x: 8 MB
  short* Qw = xb + TOKD;         // 8 MB (z=0, pre-scaled by QSCALE)
  short* Kw = Qw + TOKD;         // 8 MB (z=1)
  short* Vtw = Kw + TOKD;        // 8 MB Vt[b][n][s], masked rows zeroed
  short* Cw = Vtw + TOKD;        // 8 MB  (total 48 MB of ws)

  prep<<<dim3(16, 16, 5), 256, 0, stream>>>(x, xb, Wq, Wk, Wv, Wo, Wt);
  gemm128<false, true, 128><<<dim3(M_TOK / 128, D_MODEL / 128, 3), 256, 0, stream>>>(
      xb, Wt, bq, bk, bv, Qw, Vtw, pm);
  attn_flash<<<dim3(SEQ / 128, NHEAD, BATCH), 512, 0, stream>>>(Qw, Kw, Vtw, pm, Cw);
  gemm128<true, false, 64><<<dim3(M_TOK / 128, D_MODEL / 64, 1), 256, 0, stream>>>(
      Cw, Wt + 3 * WMAT, bo, bo, bo, d_out, nullptr, nullptr);
}

// Round 2
// 209.491 us; speedup vs baseline: 1.0674x; 1.0232x over previous
//
#include <hip/hip_runtime.h>
#include <hip/hip_bf16.h>
#include <stdint.h>
#include <math.h>

// Problem constants
#define D_MODEL 1024
#define NHEAD   16
#define DHEAD   64
#define BATCH   2
#define SEQ     2048
#define M_TOK   (BATCH * SEQ)   // 4096 tokens

// Q pre-scale: 1/sqrt(DHEAD) * log2(e), folded into the Q projection so the
// QK^T MFMA result is directly the exp2 argument.
#define QSCALE 0.18033688011112042f

typedef __attribute__((ext_vector_type(8))) short   short8;
typedef __attribute__((ext_vector_type(8))) __bf16  bf16x8;
typedef __attribute__((ext_vector_type(4))) float   f32x4;

__device__ inline short f2bf(float f) {           // RNE
  unsigned int u = __builtin_bit_cast(unsigned int, f);
  unsigned int r = (u + 0x7FFFu + ((u >> 16) & 1u)) >> 16;
  return (short)(unsigned short)r;
}
__device__ inline short f2bf_fast(float f) {      // round-nearest (ties away), 2 ops
  unsigned int u = __builtin_bit_cast(unsigned int, f);
  return (short)(unsigned short)((u + 0x8000u) >> 16);
}

// async global -> LDS, 16B per lane. LDS dest must be wave-uniform base + lane*16.
__device__ inline void gl_lds16(const void* g, void* l) {
  __builtin_amdgcn_global_load_lds((__attribute__((address_space(1))) void*)(g),
                                   (__attribute__((address_space(3))) void*)(l),
                                   16, 0, 0);
}

__device__ inline bf16x8 lds_frag(const short* p) {
  return *(const bf16x8*)(p);
}
// 8-byte-aligned fragment load (two b64 reads) for the 68-stride P slab
__device__ inline bf16x8 lds_frag64(const short* p) {
  union { bf16x8 v; short4 h[2]; } u;
  u.h[0] = *(const short4*)(p);
  u.h[1] = *(const short4*)(p + 4);
  return u.v;
}

// ---------------------------------------------------------------------------
// Prep kernel (fused): z=0..3 -> transpose+convert weight matrix z
// (W[k][n] fp32 -> Wt[n][k] bf16); z=4 -> convert x fp32 -> bf16.
// Grid (16,16,5), 256 threads. One launch instead of two.
// ---------------------------------------------------------------------------
__global__ __launch_bounds__(256) void prep(const float* __restrict__ x,
                                            short* __restrict__ xb,
                                            const float* __restrict__ w0,
                                            const float* __restrict__ w1,
                                            const float* __restrict__ w2,
                                            const float* __restrict__ w3,
                                            short* __restrict__ out) {
  const int t = threadIdx.x;
  if (blockIdx.z == 4) {
    // convert x: 256 blocks (by*16+bx), 16384 elems each
    size_t base = ((size_t)blockIdx.y * 16 + blockIdx.x) * 16384;
    const float* in = x + base;
    short* o = xb + base;
#pragma unroll
    for (int i = 0; i < 16; ++i) {
      f32x4 v = *(const f32x4*)(in + (size_t)t * 4 + i * 1024);
      short4 s4;
      s4.x = f2bf(v[0]); s4.y = f2bf(v[1]); s4.z = f2bf(v[2]); s4.w = f2bf(v[3]);
      *(short4*)(o + (size_t)t * 4 + i * 1024) = s4;
    }
    return;
  }
  __shared__ short tile[64][72];
  const float* W = blockIdx.z == 0 ? w0 : blockIdx.z == 1 ? w1 : blockIdx.z == 2 ? w2 : w3;
  short* O = out + (size_t)blockIdx.z * (D_MODEL * (size_t)D_MODEL);
  int n0 = blockIdx.x * 64, k0 = blockIdx.y * 64;
#pragma unroll
  for (int i = 0; i < 16; ++i) {
    int idx = t + 256 * i;
    int r = idx >> 6, c = idx & 63;
    tile[r][c] = f2bf(W[(size_t)(k0 + r) * D_MODEL + n0 + c]);
  }
  __syncthreads();
#pragma unroll
  for (int i = 0; i < 16; ++i) {
    int idx = t + 256 * i;
    int r = idx >> 6, c = idx & 63;
    O[(size_t)(n0 + r) * D_MODEL + k0 + c] = tile[c][r];
  }
}

// ---------------------------------------------------------------------------
// GEMM: out[m][n] = A[m][k] * Bt[n][k]^T + bias[n]  (bf16 in, fp32 acc)
// 128xTN tile, BK=64, 256 threads (4 waves, 64x(TN/2) per wave).
// LDS XOR-chunk swizzled. TN=128 for QKV (768 blocks), TN=64 for the output
// projection (512 blocks = 2/CU). [R8 best-measured configuration]
// QKV launch (VT=true): z=0 -> Q scaled by QSCALE; z=2 -> V written transposed
// with MASKED KEY ROWS ZEROED (pm[b][s]==1 -> 0).
// ---------------------------------------------------------------------------
template <bool OUTF32, bool VT, int TN>
__global__ __launch_bounds__(256) void gemm128(const short* __restrict__ A,
                                               const short* __restrict__ Bt_base,
                                               const float* __restrict__ b0,
                                               const float* __restrict__ b1,
                                               const float* __restrict__ b2,
                                               void* __restrict__ out_base,
                                               short* __restrict__ vt,
                                               const int* __restrict__ pm) {
  constexpr int NI = TN / 32;      // per-wave n-subtiles (4 or 2)
  const int z = blockIdx.z;
  const short* Bt   = Bt_base + (size_t)z * (D_MODEL * (size_t)D_MODEL);
  const float* bias = (z == 0) ? b0 : (z == 1) ? b1 : b2;

  __shared__ short As[128 * 64];   // [row][k] 64-wide rows, swizzled
  __shared__ short Bs[TN * 64];    // [n][k], swizzled

  const int t = threadIdx.x;
  const int lane = t & 63;
  const int wid = t >> 6;
  const int wm = (wid >> 1) * 64, wn = (wid & 1) * (TN / 2);
  const int m0 = blockIdx.x * 128, n0 = blockIdx.y * TN;
  const int cl = lane & 15, q = lane >> 4;
  const int sw = cl & 7;

  f32x4 acc[4][NI];
#pragma unroll
  for (int i = 0; i < 4; ++i)
#pragma unroll
    for (int j = 0; j < NI; ++j) acc[i][j] = 0.0f;

  for (int k0 = 0; k0 < D_MODEL; k0 += 64) {
    __syncthreads();
#pragma unroll
    for (int i = 0; i < 4; ++i) {   // A: 1024 chunks
      int c = t + 256 * i;
      int row = c >> 3, cp = c & 7;
      int col = ((cp ^ (row & 7)) * 8);
      gl_lds16(A + (size_t)(m0 + row) * D_MODEL + k0 + col, (void*)(As + c * 8));
    }
#pragma unroll
    for (int i = 0; i < NI; ++i) {  // B: TN*8 chunks
      int c = t + 256 * i;
      int row = c >> 3, cp = c & 7;
      int col = ((cp ^ (row & 7)) * 8);
      gl_lds16(Bt + (size_t)(n0 + row) * D_MODEL + k0 + col, (void*)(Bs + c * 8));
    }
    __syncthreads();

    bf16x8 af[4][2], bfr[NI][2];
#pragma unroll
    for (int mi = 0; mi < 4; ++mi) {
      af[mi][0] = lds_frag(As + (wm + mi * 16 + cl) * 64 + (q ^ sw) * 8);
      af[mi][1] = lds_frag(As + (wm + mi * 16 + cl) * 64 + ((4 + q) ^ sw) * 8);
    }
#pragma unroll
    for (int ni = 0; ni < NI; ++ni) {
      bfr[ni][0] = lds_frag(Bs + (wn + ni * 16 + cl) * 64 + (q ^ sw) * 8);
      bfr[ni][1] = lds_frag(Bs + (wn + ni * 16 + cl) * 64 + ((4 + q) ^ sw) * 8);
    }
#pragma unroll
    for (int mi = 0; mi < 4; ++mi)
#pragma unroll
      for (int ni = 0; ni < NI; ++ni) {
        acc[mi][ni] = __builtin_amdgcn_mfma_f32_16x16x32_bf16(af[mi][0], bfr[ni][0], acc[mi][ni], 0, 0, 0);
        acc[mi][ni] = __builtin_amdgcn_mfma_f32_16x16x32_bf16(af[mi][1], bfr[ni][1], acc[mi][ni], 0, 0, 0);
      }
  }

  // Epilogue: C/D layout col=lane&15, row=(lane>>4)*4+reg
  const float oscale = (VT && z == 0) ? QSCALE : 1.0f;
  int4 mm[4];
  if (VT && z == 2) {
#pragma unroll
    for (int mi = 0; mi < 4; ++mi) {
      int rbase = m0 + wm + mi * 16 + q * 4;
      mm[mi] = *(const int4*)(pm + (size_t)(rbase >> 11) * SEQ + (rbase & (SEQ - 1)));
    }
  }
#pragma unroll
  for (int ni = 0; ni < NI; ++ni) {
    int col = n0 + wn + ni * 16 + cl;
    float bv = bias[col];
#pragma unroll
    for (int mi = 0; mi < 4; ++mi) {
      int rbase = m0 + wm + mi * 16 + q * 4;
      if (VT && z == 2) {
        short4 o4;
        o4.x = (mm[mi].x == 1) ? (short)0 : f2bf_fast(acc[mi][ni][0] + bv);
        o4.y = (mm[mi].y == 1) ? (short)0 : f2bf_fast(acc[mi][ni][1] + bv);
        o4.z = (mm[mi].z == 1) ? (short)0 : f2bf_fast(acc[mi][ni][2] + bv);
        o4.w = (mm[mi].w == 1) ? (short)0 : f2bf_fast(acc[mi][ni][3] + bv);
        int btok = rbase >> 11;           // token block -> batch
        int s    = rbase & (SEQ - 1);
        *(short4*)(vt + (size_t)btok * ((size_t)D_MODEL * SEQ) + (size_t)col * SEQ + s) = o4;
      } else {
#pragma unroll
        for (int r = 0; r < 4; ++r) {
          float v = (acc[mi][ni][r] + bv) * oscale;
          size_t idx = (size_t)(rbase + r) * D_MODEL + col;
          if (OUTF32) {
            ((float*)out_base)[idx] = v;
          } else {
            short* out = (short*)out_base + (size_t)z * ((size_t)M_TOK * D_MODEL);
            out[idx] = f2bf_fast(v);
          }
        }
      }
    }
  }
}

// ---------------------------------------------------------------------------
// Flash attention v6: v5 (512 thr, in-block KV-split) + T14 async-STAGE split.
// R1 counters: occupancy 2x'd (19->34%) but dur only -9% (78.7->71.6us);
// VALU 50%, MFMA 22%, HBM 14%, LDS ~30% -> nothing saturated => the per-tile
// barrier-serialized stalls dominate:
//   (a) gl_lds staging issued between sync1/sync2; sync2 drains vmcnt(0) ->
//       full K/V load latency paid serially every tile;
//   (b) mask[] global read for Us in the same window;
//   (c) exp2f (no fast-math) ~5 VALU ops with range fixup.
// Fixes: (a) reg-staged prefetch -- issue global_load_dwordx4 for tile t+1
// right after sync2, latency hides under tile t's compute; ds_write the regs
// after sync1 (T14, +17% attn per guide G15). (b) hoist the full u[] vector
// (SEQ bf16, 4KB LDS) once at kernel start. (c) raw v_exp_f32 builtin
// (scores bounded; no fixup needed).
// ---------------------------------------------------------------------------
__global__ __launch_bounds__(512) void attn_flash(const short* __restrict__ Q,
                                                  const short* __restrict__ K,
                                                  const short* __restrict__ Vt,
                                                  const int*   __restrict__ mask,
                                                  short* __restrict__ ctx) {
  const int qb = blockIdx.x;   // 0..15
  const int h  = blockIdx.y;   // 0..15
  const int b  = blockIdx.z;   // 0..1

  // union: Q stage (8192 shorts) / P slabs 8 x 32x68 (17408 shorts)
  //        / epilogue redO (4*64*32 f32 = 32768B)
  __shared__ __align__(16) short QPs[17408];
  __shared__ __align__(16) short Ks[2 * 64 * 64];   // [half][key][d] swizzled; epi: redL
  __shared__ __align__(16) short Vts[2 * 64 * 64];  // [half][d][key] swizzled
  __shared__ __align__(16) short Usall[SEQ];        // u[key] = mask?0:1, whole seq

  const int t = threadIdx.x;
  const int lane = t & 63;
  const int wid = t >> 6;           // 0..7
  const int wg  = wid >> 1;         // row-group 0..3 (32 q-rows each)
  const int kvh = wid & 1;          // kv half: keys [kvh*1024, kvh*1024+1024)
  const int cl = lane & 15, q = lane >> 4;
  const int sw = cl & 7;

  const size_t rowQ0 = (size_t)b * SEQ + (size_t)qb * 128;
  const size_t rowK0 = (size_t)b * SEQ;
  const size_t vbase = ((size_t)b * D_MODEL + h * DHEAD) * SEQ;

  // per-thread staging addresses (same swizzle as the old gl_lds mapping:
  // thread t owns LDS chunk t*16B; global source pre-swizzled)
  const int srow = t >> 3, scp = t & 7;
  const int scol = (scp ^ (srow & 7)) * 8;
  const short* Kg0 = K + (rowK0 + srow) * D_MODEL + h * DHEAD + scol;
  const short* Kg1 = K + (rowK0 + 1024 + srow) * D_MODEL + h * DHEAD + scol;
  const short* Vg0 = Vt + vbase + (size_t)srow * SEQ + scol;
  const short* Vg1 = Vt + vbase + (size_t)srow * SEQ + 1024 + scol;

  // prologue: issue tile-0 K/V prefetch (lands during Q staging)
  short8 gk0 = *(const short8*)(Kg0);
  short8 gk1 = *(const short8*)(Kg1);
  short8 gv0 = *(const short8*)(Vg0);
  short8 gv1 = *(const short8*)(Vg1);

  // hoist the mask -> u bf16 vector for the whole sequence (once)
#pragma unroll
  for (int i = 0; i < 4; ++i) {
    int idx = t + 512 * i;
    Usall[idx] = (mask[(size_t)b * SEQ + idx] == 1) ? (short)0 : (short)0x3F80;
  }

  // stage Q tile (128 rows x 64 d), swizzled, into the union region
#pragma unroll
  for (int i = 0; i < 2; ++i) {
    int c = t + 512 * i;
    int row = c >> 3, cp = c & 7;
    gl_lds16(Q + (rowQ0 + row) * D_MODEL + h * DHEAD + ((cp ^ (row & 7)) * 8),
             (void*)(QPs + c * 8));
  }
  __syncthreads();

  // Register-resident Q fragments: wave owns rows [32*wg, 32*wg+32)
  bf16x8 qf[2][2];
#pragma unroll
  for (int rb = 0; rb < 2; ++rb) {
    int row = wg * 32 + rb * 16 + cl;
    qf[rb][0] = lds_frag(QPs + row * 64 + (q ^ sw) * 8);
    qf[rb][1] = lds_frag(QPs + row * 64 + ((4 + q) ^ sw) * 8);
  }
  short* Psw = QPs + wid * (32 * 68);   // wave-private P slab, stride 68
  const short* Kp = Ks  + kvh * 4096;
  const short* Vp = Vts + kvh * 4096;

  f32x4 lacc[2], oacc[2][4];
#pragma unroll
  for (int rb = 0; rb < 2; ++rb) {
    lacc[rb] = 0.0f;
#pragma unroll
    for (int dj = 0; dj < 4; ++dj) oacc[rb][dj] = 0.0f;
  }

  for (int s0 = 0; s0 < 1024; s0 += 64) {
    __syncthreads();   // prior tile's LDS reads done (also orders qf/Usall init)

    // write the prefetched K/V regs into the (single-buffered) LDS tiles
    *(short8*)(Ks  + t * 8)        = gk0;
    *(short8*)(Ks  + 4096 + t * 8) = gk1;
    *(short8*)(Vts + t * 8)        = gv0;
    *(short8*)(Vts + 4096 + t * 8) = gv1;
    __syncthreads();

    // issue next tile's prefetch; latency hides under this tile's compute
    if (s0 + 64 < 1024) {
      int sn = s0 + 64;
      gk0 = *(const short8*)(Kg0 + (size_t)sn * D_MODEL);
      gk1 = *(const short8*)(Kg1 + (size_t)sn * D_MODEL);
      gv0 = *(const short8*)(Vg0 + sn);
      gv1 = *(const short8*)(Vg1 + sn);
    }

    const short* Up = Usall + kvh * 1024 + s0;

    // S~ = Qs K^T  (C-layout: row = q*4+r, col = j*16+cl); K frags feed both rb
    f32x4 s[2][4];
#pragma unroll
    for (int j = 0; j < 4; ++j) {
      bf16x8 kf0 = lds_frag(Kp + (j * 16 + cl) * 64 + (q ^ sw) * 8);
      bf16x8 kf1 = lds_frag(Kp + (j * 16 + cl) * 64 + ((4 + q) ^ sw) * 8);
#pragma unroll
      for (int rb = 0; rb < 2; ++rb) {
        f32x4 sa = 0.0f;
        sa = __builtin_amdgcn_mfma_f32_16x16x32_bf16(qf[rb][0], kf0, sa, 0, 0, 0);
        sa = __builtin_amdgcn_mfma_f32_16x16x32_bf16(qf[rb][1], kf1, sa, 0, 0, 0);
        s[rb][j] = sa;
      }
    }

    // p = exp2(s): raw v_exp_f32 (scores bounded). Write P slab.
#pragma unroll
    for (int rb = 0; rb < 2; ++rb)
#pragma unroll
      for (int j = 0; j < 4; ++j)
#pragma unroll
        for (int r = 0; r < 4; ++r)
          Psw[(rb * 16 + q * 4 + r) * 68 + j * 16 + cl] =
              f2bf_fast(__builtin_amdgcn_exp2f(s[rb][j][r]));

    // Pin order: P-slab stores must not be reordered after the pf loads
    // (cross-lane RAW through LDS; per-thread alias analysis can't see it).
    asm volatile("" ::: "memory");

    // O += P V ; l += P u  (V/u frags feed both rb)
    bf16x8 pf[2][2];
#pragma unroll
    for (int rb = 0; rb < 2; ++rb) {
      pf[rb][0] = lds_frag64(Psw + (rb * 16 + cl) * 68 + q * 8);
      pf[rb][1] = lds_frag64(Psw + (rb * 16 + cl) * 68 + 32 + q * 8);
    }
    bf16x8 uf0 = lds_frag(Up + q * 8);          // broadcast across cl: conflict-free
    bf16x8 uf1 = lds_frag(Up + 32 + q * 8);
#pragma unroll
    for (int dj = 0; dj < 4; ++dj) {
      bf16x8 vf0 = lds_frag(Vp + (dj * 16 + cl) * 64 + (q ^ sw) * 8);
      bf16x8 vf1 = lds_frag(Vp + (dj * 16 + cl) * 64 + ((4 + q) ^ sw) * 8);
#pragma unroll
      for (int rb = 0; rb < 2; ++rb) {
        oacc[rb][dj] = __builtin_amdgcn_mfma_f32_16x16x32_bf16(pf[rb][0], vf0, oacc[rb][dj], 0, 0, 0);
        oacc[rb][dj] = __builtin_amdgcn_mfma_f32_16x16x32_bf16(pf[rb][1], vf1, oacc[rb][dj], 0, 0, 0);
      }
    }
#pragma unroll
    for (int rb = 0; rb < 2; ++rb) {
      lacc[rb] = __builtin_amdgcn_mfma_f32_16x16x32_bf16(pf[rb][0], uf0, lacc[rb], 0, 0, 0);
      lacc[rb] = __builtin_amdgcn_mfma_f32_16x16x32_bf16(pf[rb][1], uf1, lacc[rb], 0, 0, 0);
    }
  }

  // ---- combine kv-halves through LDS (O,l are linear in the key axis) ----
  __syncthreads();                    // all compute reads of LDS done
  float* redO = (float*)QPs;          // 32768B needed <= 34816B
  float* redL = (float*)Ks;           // 8192B needed <= 16384B
  const int rbase = (wg * 64 + lane) * 32;
  const int lbase = (wg * 64 + lane) * 8;
  if (kvh) {
#pragma unroll
    for (int rb = 0; rb < 2; ++rb) {
#pragma unroll
      for (int dj = 0; dj < 4; ++dj) {
        int qi = (rb * 4 + dj) ^ (lane & 7);   // XOR-swizzle: spread banks
        *(f32x4*)(redO + rbase + qi * 4) = oacc[rb][dj];
      }
      *(f32x4*)(redL + lbase + rb * 4) = lacc[rb];
    }
  }
  __syncthreads();
  if (kvh) return;
#pragma unroll
  for (int rb = 0; rb < 2; ++rb) {
    lacc[rb] += *(const f32x4*)(redL + lbase + rb * 4);
#pragma unroll
    for (int dj = 0; dj < 4; ++dj) {
      int qi = (rb * 4 + dj) ^ (lane & 7);
      oacc[rb][dj] += *(const f32x4*)(redO + rbase + qi * 4);
    }
  }

  // finalize: l = lacc (full row-sum, same C-layout rows), O/l, store
#pragma unroll
  for (int rb = 0; rb < 2; ++rb)
#pragma unroll
    for (int dj = 0; dj < 4; ++dj)
#pragma unroll
      for (int r = 0; r < 4; ++r) {
        float lv = lacc[rb][r];
        float o = (lv > 0.0f) ? oacc[rb][dj][r] / lv : 0.0f;
        size_t row = rowQ0 + wg * 32 + rb * 16 + q * 4 + r;
        ctx[row * D_MODEL + h * DHEAD + dj * 16 + cl] = f2bf(o);
      }
}

// ---------------------------------------------------------------------------
extern "C" void kernel_launch(void* const* d_in, const int* in_sizes, int n_in,
                              void* d_out, int out_size, void* d_ws, size_t ws_size,
                              hipStream_t stream) {
  (void)in_sizes; (void)n_in; (void)out_size; (void)ws_size;

  const float* x  = (const float*)d_in[0];
  const int*   pm = (const int*)  d_in[1];
  const float* Wq = (const float*)d_in[2];
  const float* bq = (const float*)d_in[3];
  const float* Wk = (const float*)d_in[4];
  const float* bk = (const float*)d_in[5];
  const float* Wv = (const float*)d_in[6];
  const float* bv = (const float*)d_in[7];
  const float* Wo = (const float*)d_in[8];
  const float* bo = (const float*)d_in[9];

  const size_t WMAT = (size_t)D_MODEL * D_MODEL;   // 1M elems
  const size_t TOKD = (size_t)M_TOK * D_MODEL;     // 4M elems

  short* base = (short*)d_ws;
  short* Wt = base;              // 4 transposed bf16 weights: 8 MB
  short* xb = base + 4 * WMAT;   // bf16 x: 8 MB
  short* Qw = xb + TOKD;         // 8 MB (z=0, pre-scaled by QSCALE)
  short* Kw = Qw + TOKD;         // 8 MB (z=1)
  short* Vtw = Kw + TOKD;        // 8 MB Vt[b][n][s], masked rows zeroed
  short* Cw = Vtw + TOKD;        // 8 MB  (total 48 MB of ws)

  prep<<<dim3(16, 16, 5), 256, 0, stream>>>(x, xb, Wq, Wk, Wv, Wo, Wt);
  gemm128<false, true, 128><<<dim3(M_TOK / 128, D_MODEL / 128, 3), 256, 0, stream>>>(
      xb, Wt, bq, bk, bv, Qw, Vtw, pm);
  attn_flash<<<dim3(SEQ / 128, NHEAD, BATCH), 512, 0, stream>>>(Qw, Kw, Vtw, pm, Cw);
  gemm128<true, false, 64><<<dim3(M_TOK / 128, D_MODEL / 64, 1), 256, 0, stream>>>(
      Cw, Wt + 3 * WMAT, bo, bo, bo, d_out, nullptr, nullptr);
}

// Round 3
// 207.898 us; speedup vs baseline: 1.0755x; 1.0077x over previous
//
#include <hip/hip_runtime.h>
#include <hip/hip_bf16.h>
#include <stdint.h>
#include <math.h>

// Problem constants
#define D_MODEL 1024
#define NHEAD   16
#define DHEAD   64
#define BATCH   2
#define SEQ     2048
#define M_TOK   (BATCH * SEQ)   // 4096 tokens

// Q pre-scale: 1/sqrt(DHEAD) * log2(e), folded into the Q projection so the
// QK^T MFMA result is directly the exp2 argument.
#define QSCALE 0.18033688011112042f

typedef __attribute__((ext_vector_type(8))) short   short8;
typedef __attribute__((ext_vector_type(8))) __bf16  bf16x8;
typedef __attribute__((ext_vector_type(4))) float   f32x4;

__device__ inline short f2bf(float f) {           // RNE
  unsigned int u = __builtin_bit_cast(unsigned int, f);
  unsigned int r = (u + 0x7FFFu + ((u >> 16) & 1u)) >> 16;
  return (short)(unsigned short)r;
}
__device__ inline short f2bf_fast(float f) {      // round-nearest (ties away), 2 ops
  unsigned int u = __builtin_bit_cast(unsigned int, f);
  return (short)(unsigned short)((u + 0x8000u) >> 16);
}

// async global -> LDS, 16B per lane. LDS dest must be wave-uniform base + lane*16.
__device__ inline void gl_lds16(const void* g, void* l) {
  __builtin_amdgcn_global_load_lds((__attribute__((address_space(1))) void*)(g),
                                   (__attribute__((address_space(3))) void*)(l),
                                   16, 0, 0);
}

__device__ inline bf16x8 lds_frag(const short* p) {
  return *(const bf16x8*)(p);
}
// fragment assembled from two 8-byte LDS reads at independent addresses
__device__ inline bf16x8 lds_frag2x64(const short* p1, const short* p2) {
  union { bf16x8 v; short4 h[2]; } u;
  u.h[0] = *(const short4*)(p1);
  u.h[1] = *(const short4*)(p2);
  return u.v;
}

// ---------------------------------------------------------------------------
// Prep kernel (fused): z=0..3 -> transpose+convert weight matrix z
// (W[k][n] fp32 -> Wt[n][k] bf16); z=4 -> convert x fp32 -> bf16.
// Grid (16,16,5), 256 threads. One launch instead of two.
// ---------------------------------------------------------------------------
__global__ __launch_bounds__(256) void prep(const float* __restrict__ x,
                                            short* __restrict__ xb,
                                            const float* __restrict__ w0,
                                            const float* __restrict__ w1,
                                            const float* __restrict__ w2,
                                            const float* __restrict__ w3,
                                            short* __restrict__ out) {
  const int t = threadIdx.x;
  if (blockIdx.z == 4) {
    // convert x: 256 blocks (by*16+bx), 16384 elems each
    size_t base = ((size_t)blockIdx.y * 16 + blockIdx.x) * 16384;
    const float* in = x + base;
    short* o = xb + base;
#pragma unroll
    for (int i = 0; i < 16; ++i) {
      f32x4 v = *(const f32x4*)(in + (size_t)t * 4 + i * 1024);
      short4 s4;
      s4.x = f2bf(v[0]); s4.y = f2bf(v[1]); s4.z = f2bf(v[2]); s4.w = f2bf(v[3]);
      *(short4*)(o + (size_t)t * 4 + i * 1024) = s4;
    }
    return;
  }
  __shared__ short tile[64][72];
  const float* W = blockIdx.z == 0 ? w0 : blockIdx.z == 1 ? w1 : blockIdx.z == 2 ? w2 : w3;
  short* O = out + (size_t)blockIdx.z * (D_MODEL * (size_t)D_MODEL);
  int n0 = blockIdx.x * 64, k0 = blockIdx.y * 64;
#pragma unroll
  for (int i = 0; i < 16; ++i) {
    int idx = t + 256 * i;
    int r = idx >> 6, c = idx & 63;
    tile[r][c] = f2bf(W[(size_t)(k0 + r) * D_MODEL + n0 + c]);
  }
  __syncthreads();
#pragma unroll
  for (int i = 0; i < 16; ++i) {
    int idx = t + 256 * i;
    int r = idx >> 6, c = idx & 63;
    O[(size_t)(n0 + r) * D_MODEL + k0 + c] = tile[c][r];
  }
}

// ---------------------------------------------------------------------------
// GEMM: out[m][n] = A[m][k] * Bt[n][k]^T + bias[n]  (bf16 in, fp32 acc)
// 128xTN tile, BK=64, 256 threads (4 waves, 64x(TN/2) per wave).
// LDS XOR-chunk swizzled. TN=128 for QKV (768 blocks), TN=64 for the output
// projection (512 blocks = 2/CU). [R8 best-measured configuration]
// QKV launch (VT=true): z=0 -> Q scaled by QSCALE; z=2 -> V written transposed
// with MASKED KEY ROWS ZEROED (pm[b][s]==1 -> 0).
// ---------------------------------------------------------------------------
template <bool OUTF32, bool VT, int TN>
__global__ __launch_bounds__(256) void gemm128(const short* __restrict__ A,
                                               const short* __restrict__ Bt_base,
                                               const float* __restrict__ b0,
                                               const float* __restrict__ b1,
                                               const float* __restrict__ b2,
                                               void* __restrict__ out_base,
                                               short* __restrict__ vt,
                                               const int* __restrict__ pm) {
  constexpr int NI = TN / 32;      // per-wave n-subtiles (4 or 2)
  const int z = blockIdx.z;
  const short* Bt   = Bt_base + (size_t)z * (D_MODEL * (size_t)D_MODEL);
  const float* bias = (z == 0) ? b0 : (z == 1) ? b1 : b2;

  __shared__ short As[128 * 64];   // [row][k] 64-wide rows, swizzled
  __shared__ short Bs[TN * 64];    // [n][k], swizzled

  const int t = threadIdx.x;
  const int lane = t & 63;
  const int wid = t >> 6;
  const int wm = (wid >> 1) * 64, wn = (wid & 1) * (TN / 2);
  const int m0 = blockIdx.x * 128, n0 = blockIdx.y * TN;
  const int cl = lane & 15, q = lane >> 4;
  const int sw = cl & 7;

  f32x4 acc[4][NI];
#pragma unroll
  for (int i = 0; i < 4; ++i)
#pragma unroll
    for (int j = 0; j < NI; ++j) acc[i][j] = 0.0f;

  for (int k0 = 0; k0 < D_MODEL; k0 += 64) {
    __syncthreads();
#pragma unroll
    for (int i = 0; i < 4; ++i) {   // A: 1024 chunks
      int c = t + 256 * i;
      int row = c >> 3, cp = c & 7;
      int col = ((cp ^ (row & 7)) * 8);
      gl_lds16(A + (size_t)(m0 + row) * D_MODEL + k0 + col, (void*)(As + c * 8));
    }
#pragma unroll
    for (int i = 0; i < NI; ++i) {  // B: TN*8 chunks
      int c = t + 256 * i;
      int row = c >> 3, cp = c & 7;
      int col = ((cp ^ (row & 7)) * 8);
      gl_lds16(Bt + (size_t)(n0 + row) * D_MODEL + k0 + col, (void*)(Bs + c * 8));
    }
    __syncthreads();

    bf16x8 af[4][2], bfr[NI][2];
#pragma unroll
    for (int mi = 0; mi < 4; ++mi) {
      af[mi][0] = lds_frag(As + (wm + mi * 16 + cl) * 64 + (q ^ sw) * 8);
      af[mi][1] = lds_frag(As + (wm + mi * 16 + cl) * 64 + ((4 + q) ^ sw) * 8);
    }
#pragma unroll
    for (int ni = 0; ni < NI; ++ni) {
      bfr[ni][0] = lds_frag(Bs + (wn + ni * 16 + cl) * 64 + (q ^ sw) * 8);
      bfr[ni][1] = lds_frag(Bs + (wn + ni * 16 + cl) * 64 + ((4 + q) ^ sw) * 8);
    }
#pragma unroll
    for (int mi = 0; mi < 4; ++mi)
#pragma unroll
      for (int ni = 0; ni < NI; ++ni) {
        acc[mi][ni] = __builtin_amdgcn_mfma_f32_16x16x32_bf16(af[mi][0], bfr[ni][0], acc[mi][ni], 0, 0, 0);
        acc[mi][ni] = __builtin_amdgcn_mfma_f32_16x16x32_bf16(af[mi][1], bfr[ni][1], acc[mi][ni], 0, 0, 0);
      }
  }

  // Epilogue: C/D layout col=lane&15, row=(lane>>4)*4+reg
  const float oscale = (VT && z == 0) ? QSCALE : 1.0f;
  int4 mm[4];
  if (VT && z == 2) {
#pragma unroll
    for (int mi = 0; mi < 4; ++mi) {
      int rbase = m0 + wm + mi * 16 + q * 4;
      mm[mi] = *(const int4*)(pm + (size_t)(rbase >> 11) * SEQ + (rbase & (SEQ - 1)));
    }
  }
#pragma unroll
  for (int ni = 0; ni < NI; ++ni) {
    int col = n0 + wn + ni * 16 + cl;
    float bv = bias[col];
#pragma unroll
    for (int mi = 0; mi < 4; ++mi) {
      int rbase = m0 + wm + mi * 16 + q * 4;
      if (VT && z == 2) {
        short4 o4;
        o4.x = (mm[mi].x == 1) ? (short)0 : f2bf_fast(acc[mi][ni][0] + bv);
        o4.y = (mm[mi].y == 1) ? (short)0 : f2bf_fast(acc[mi][ni][1] + bv);
        o4.z = (mm[mi].z == 1) ? (short)0 : f2bf_fast(acc[mi][ni][2] + bv);
        o4.w = (mm[mi].w == 1) ? (short)0 : f2bf_fast(acc[mi][ni][3] + bv);
        int btok = rbase >> 11;           // token block -> batch
        int s    = rbase & (SEQ - 1);
        *(short4*)(vt + (size_t)btok * ((size_t)D_MODEL * SEQ) + (size_t)col * SEQ + s) = o4;
      } else {
#pragma unroll
        for (int r = 0; r < 4; ++r) {
          float v = (acc[mi][ni][r] + bv) * oscale;
          size_t idx = (size_t)(rbase + r) * D_MODEL + col;
          if (OUTF32) {
            ((float*)out_base)[idx] = v;
          } else {
            short* out = (short*)out_base + (size_t)z * ((size_t)M_TOK * D_MODEL);
            out[idx] = f2bf_fast(v);
          }
        }
      }
    }
  }
}

// ---------------------------------------------------------------------------
// Flash attention v7: in-register P (no LDS P slab).
// R2 diagnosis: LDS pipe ~80% busy (cycle model: ~470 LDS-cy/wave/tile, 16
// waves/CU -> ~120k of 150k kernel cy) while VALU 27%/MFMA 24%/HBM 16%.
// Dominant term was the P round-trip (32 scalar b16 writes + b64 reads).
// v7 structure:
//  - swapped QK^T: s^T = mfma(kf, qf) -> lane holds P[q=cl][keys 16j+4g+r]
//    (g=lane>>4). q is lane-local => P can feed PV's B-operand directly.
//  - key-order freedom: PV sums over keys, so the MFMA k-slot ordering is
//    arbitrary as long as V fragments use the SAME ordering. Choose
//    k-slot(g,jj) = key 32c + 16*(jj>>2) + 4g + (jj&3): P packs lane-locally
//    (pf[c] = [p[2c][0..3], p[2c+1][0..3]]), V frags become two b64 reads at
//    the matching offsets. Zero cross-lane ops, zero P LDS traffic.
//  - mask as multiplicative u (f32 LDS, broadcast f32x4 reads); l becomes
//    register f32x4 accumulation (+ one shfl reduce at the end); the u-MFMAs
//    and Us bf16 reads are gone.
//  - output lands transposed (d on the reg axis) -> 8 short4 stores vs 32
//    scalar stores.
// New LDS budget ~300 cy/wave/tile (-36%); LDS 57.3 KB (2 blocks/CU kept).
// ---------------------------------------------------------------------------
__global__ __launch_bounds__(512) void attn_flash(const short* __restrict__ Q,
                                                  const short* __restrict__ K,
                                                  const short* __restrict__ Vt,
                                                  const int*   __restrict__ mask,
                                                  short* __restrict__ ctx) {
  const int qb = blockIdx.x;   // 0..15
  const int h  = blockIdx.y;   // 0..15
  const int b  = blockIdx.z;   // 0..1

  // layout (shorts): Qs[8192] | Ks[8192] | Vts[8192] | Usf(f32 2048 = 4096)
  // epilogue overlay: redO f32[8192] over Qs+Ks (32KB), redL f32 over Vts.
  __shared__ __align__(16) short smem[28672];
  short* Qs  = smem;
  short* Ks  = smem + 8192;
  short* Vts = smem + 16384;
  float* Usf = (float*)(smem + 24576);

  const int t = threadIdx.x;
  const int lane = t & 63;
  const int wid = t >> 6;           // 0..7
  const int wg  = wid >> 1;         // row-group 0..3 (32 q-rows each)
  const int kvh = wid & 1;          // kv half: keys [kvh*1024, kvh*1024+1024)
  const int cl = lane & 15, q = lane >> 4;
  const int sw = cl & 7;

  const size_t rowQ0 = (size_t)b * SEQ + (size_t)qb * 128;
  const size_t rowK0 = (size_t)b * SEQ;
  const size_t vbase = ((size_t)b * D_MODEL + h * DHEAD) * SEQ;

  // per-thread staging addresses (thread t owns LDS chunk t*16B; global
  // source pre-swizzled so LDS reads can XOR-deswizzle)
  const int srow = t >> 3, scp = t & 7;
  const int scol = (scp ^ (srow & 7)) * 8;
  const short* Kg0 = K + (rowK0 + srow) * D_MODEL + h * DHEAD + scol;
  const short* Kg1 = K + (rowK0 + 1024 + srow) * D_MODEL + h * DHEAD + scol;
  const short* Vg0 = Vt + vbase + (size_t)srow * SEQ + scol;
  const short* Vg1 = Vt + vbase + (size_t)srow * SEQ + 1024 + scol;

  // prologue: issue tile-0 K/V prefetch (lands during Q staging)
  short8 gk0 = *(const short8*)(Kg0);
  short8 gk1 = *(const short8*)(Kg1);
  short8 gv0 = *(const short8*)(Vg0);
  short8 gv1 = *(const short8*)(Vg1);

  // mask -> u f32 vector for the whole sequence (once, coalesced)
  {
    int4 mv = *(const int4*)(mask + (size_t)b * SEQ + t * 4);
    f32x4 u4;
    u4[0] = (mv.x == 1) ? 0.0f : 1.0f;
    u4[1] = (mv.y == 1) ? 0.0f : 1.0f;
    u4[2] = (mv.z == 1) ? 0.0f : 1.0f;
    u4[3] = (mv.w == 1) ? 0.0f : 1.0f;
    *(f32x4*)(Usf + t * 4) = u4;
  }

  // stage Q tile (128 rows x 64 d), swizzled
#pragma unroll
  for (int i = 0; i < 2; ++i) {
    int c = t + 512 * i;
    int row = c >> 3, cp = c & 7;
    gl_lds16(Q + (rowQ0 + row) * D_MODEL + h * DHEAD + ((cp ^ (row & 7)) * 8),
             (void*)(Qs + c * 8));
  }
  __syncthreads();

  // Register-resident Q fragments: wave owns rows [32*wg, 32*wg+32)
  bf16x8 qf[2][2];
#pragma unroll
  for (int rb = 0; rb < 2; ++rb) {
    int row = wg * 32 + rb * 16 + cl;
    qf[rb][0] = lds_frag(Qs + row * 64 + (q ^ sw) * 8);
    qf[rb][1] = lds_frag(Qs + row * 64 + ((4 + q) ^ sw) * 8);
  }
  const short* Kp = Ks  + kvh * 4096;
  const short* Vp = Vts + kvh * 4096;
  const float* Up = Usf + kvh * 1024;

  f32x4 lacc[2], oacc[2][4];
#pragma unroll
  for (int rb = 0; rb < 2; ++rb) {
    lacc[rb] = 0.0f;
#pragma unroll
    for (int dj = 0; dj < 4; ++dj) oacc[rb][dj] = 0.0f;
  }

  for (int s0 = 0; s0 < 1024; s0 += 64) {
    __syncthreads();   // prior tile's LDS reads done (also orders Qs/Usf init)

    // write the prefetched K/V regs into the (single-buffered) LDS tiles
    *(short8*)(Ks  + t * 8)        = gk0;
    *(short8*)(Ks  + 4096 + t * 8) = gk1;
    *(short8*)(Vts + t * 8)        = gv0;
    *(short8*)(Vts + 4096 + t * 8) = gv1;
    __syncthreads();

    // issue next tile's prefetch; latency hides under this tile's compute
    if (s0 + 64 < 1024) {
      int sn = s0 + 64;
      gk0 = *(const short8*)(Kg0 + (size_t)sn * D_MODEL);
      gk1 = *(const short8*)(Kg1 + (size_t)sn * D_MODEL);
      gv0 = *(const short8*)(Vg0 + sn);
      gv1 = *(const short8*)(Vg1 + sn);
    }

    // S^T = K Q^T via mfma(kf, qf): C row = key 4g+r (tile j), col = q-row cl
    f32x4 s[2][4];
#pragma unroll
    for (int j = 0; j < 4; ++j) {
      bf16x8 kf0 = lds_frag(Kp + (j * 16 + cl) * 64 + (q ^ sw) * 8);
      bf16x8 kf1 = lds_frag(Kp + (j * 16 + cl) * 64 + ((4 + q) ^ sw) * 8);
#pragma unroll
      for (int rb = 0; rb < 2; ++rb) {
        f32x4 sa = 0.0f;
        sa = __builtin_amdgcn_mfma_f32_16x16x32_bf16(kf0, qf[rb][0], sa, 0, 0, 0);
        sa = __builtin_amdgcn_mfma_f32_16x16x32_bf16(kf1, qf[rb][1], sa, 0, 0, 0);
        s[rb][j] = sa;
      }
    }

    // p = u * exp2(s) in registers; l accumulates as f32x4
    f32x4 uv[4];
#pragma unroll
    for (int j = 0; j < 4; ++j)
      uv[j] = *(const f32x4*)(Up + s0 + j * 16 + 4 * q);   // broadcast across cl
#pragma unroll
    for (int rb = 0; rb < 2; ++rb)
#pragma unroll
      for (int j = 0; j < 4; ++j) {
#pragma unroll
        for (int r = 0; r < 4; ++r)
          s[rb][j][r] = __builtin_amdgcn_exp2f(s[rb][j][r]) * uv[j][r];
        lacc[rb] += s[rb][j];
      }

    // pack P to bf16 lane-locally: pf[c] = keys {32c+4g+r} ++ {32c+16+4g+r}
    bf16x8 pf[2][2];
#pragma unroll
    for (int rb = 0; rb < 2; ++rb)
#pragma unroll
      for (int c = 0; c < 2; ++c) {
        bf16x8 v;
        v[0] = (__bf16)s[rb][2 * c][0];
        v[1] = (__bf16)s[rb][2 * c][1];
        v[2] = (__bf16)s[rb][2 * c][2];
        v[3] = (__bf16)s[rb][2 * c][3];
        v[4] = (__bf16)s[rb][2 * c + 1][0];
        v[5] = (__bf16)s[rb][2 * c + 1][1];
        v[6] = (__bf16)s[rb][2 * c + 1][2];
        v[7] = (__bf16)s[rb][2 * c + 1][3];
        pf[rb][c] = v;
      }

    // O^T += V^T P^T: A = V^T frags with k-slot(g,jj) = key
    // 32c + 16*(jj>>2) + 4g + (jj&3)  -> two b64 reads per fragment.
    const int vo = (q & 1) * 4;
#pragma unroll
    for (int dj = 0; dj < 4; ++dj) {
      const short* vrow = Vp + (dj * 16 + cl) * 64;
#pragma unroll
      for (int c = 0; c < 2; ++c) {
        int L1 = 4 * c + (q >> 1);
        int L2 = L1 + 2;
        bf16x8 vfc = lds_frag2x64(vrow + (L1 ^ sw) * 8 + vo,
                                  vrow + (L2 ^ sw) * 8 + vo);
#pragma unroll
        for (int rb = 0; rb < 2; ++rb)
          oacc[rb][dj] = __builtin_amdgcn_mfma_f32_16x16x32_bf16(vfc, pf[rb][c], oacc[rb][dj], 0, 0, 0);
      }
    }
  }

  // ---- combine kv-halves through LDS (O,l are linear in the key axis) ----
  __syncthreads();                       // all compute reads of LDS done
  float hl[2];
#pragma unroll
  for (int rb = 0; rb < 2; ++rb)
    hl[rb] = lacc[rb][0] + lacc[rb][1] + lacc[rb][2] + lacc[rb][3];

  float* redO = (float*)smem;            // 32 KB (Qs+Ks region)
  float* redL = (float*)(smem + 16384);  // 2 KB (start of Vts region)
  const int slot = wg * 64 + lane;
  if (kvh) {
#pragma unroll
    for (int rb = 0; rb < 2; ++rb) {
#pragma unroll
      for (int dj = 0; dj < 4; ++dj) {
        int qi = (rb * 4 + dj) ^ (lane & 7);   // XOR-swizzle: spread banks
        *(f32x4*)(redO + slot * 32 + qi * 4) = oacc[rb][dj];
      }
      redL[slot * 2 + rb] = hl[rb];
    }
  }
  __syncthreads();
  if (kvh) return;
#pragma unroll
  for (int rb = 0; rb < 2; ++rb) {
    hl[rb] += redL[slot * 2 + rb];
#pragma unroll
    for (int dj = 0; dj < 4; ++dj) {
      int qi = (rb * 4 + dj) ^ (lane & 7);
      oacc[rb][dj] += *(const f32x4*)(redO + slot * 32 + qi * 4);
    }
  }
  // l: sum over the 4 g-lane groups (lanes ^16, ^32 share the same cl)
#pragma unroll
  for (int rb = 0; rb < 2; ++rb) {
    hl[rb] += __shfl_xor(hl[rb], 16);
    hl[rb] += __shfl_xor(hl[rb], 32);
  }

  // finalize: O^T layout -> lane (cl,g) reg r holds O[q=wg*32+rb*16+cl]
  // [d = dj*16 + 4g + r]; 4 consecutive d per reg -> short4 stores.
#pragma unroll
  for (int rb = 0; rb < 2; ++rb) {
    float inv = (hl[rb] > 0.0f) ? 1.0f / hl[rb] : 0.0f;
    size_t row = rowQ0 + wg * 32 + rb * 16 + cl;
#pragma unroll
    for (int dj = 0; dj < 4; ++dj) {
      short4 o4;
      o4.x = f2bf(oacc[rb][dj][0] * inv);
      o4.y = f2bf(oacc[rb][dj][1] * inv);
      o4.z = f2bf(oacc[rb][dj][2] * inv);
      o4.w = f2bf(oacc[rb][dj][3] * inv);
      *(short4*)(ctx + row * D_MODEL + h * DHEAD + dj * 16 + q * 4) = o4;
    }
  }
}

// ---------------------------------------------------------------------------
extern "C" void kernel_launch(void* const* d_in, const int* in_sizes, int n_in,
                              void* d_out, int out_size, void* d_ws, size_t ws_size,
                              hipStream_t stream) {
  (void)in_sizes; (void)n_in; (void)out_size; (void)ws_size;

  const float* x  = (const float*)d_in[0];
  const int*   pm = (const int*)  d_in[1];
  const float* Wq = (const float*)d_in[2];
  const float* bq = (const float*)d_in[3];
  const float* Wk = (const float*)d_in[4];
  const float* bk = (const float*)d_in[5];
  const float* Wv = (const float*)d_in[6];
  const float* bv = (const float*)d_in[7];
  const float* Wo = (const float*)d_in[8];
  const float* bo = (const float*)d_in[9];

  const size_t WMAT = (size_t)D_MODEL * D_MODEL;   // 1M elems
  const size_t TOKD = (size_t)M_TOK * D_MODEL;     // 4M elems

  short* base = (short*)d_ws;
  short* Wt = base;              // 4 transposed bf16 weights: 8 MB
  short* xb = base + 4 * WMAT;   // bf16 x: 8 MB
  short* Qw = xb + TOKD;         // 8 MB (z=0, pre-scaled by QSCALE)
  short* Kw = Qw + TOKD;         // 8 MB (z=1)
  short* Vtw = Kw + TOKD;        // 8 MB Vt[b][n][s], masked rows zeroed
  short* Cw = Vtw + TOKD;        // 8 MB  (total 48 MB of ws)

  prep<<<dim3(16, 16, 5), 256, 0, stream>>>(x, xb, Wq, Wk, Wv, Wo, Wt);
  gemm128<false, true, 128><<<dim3(M_TOK / 128, D_MODEL / 128, 3), 256, 0, stream>>>(
      xb, Wt, bq, bk, bv, Qw, Vtw, pm);
  attn_flash<<<dim3(SEQ / 128, NHEAD, BATCH), 512, 0, stream>>>(Qw, Kw, Vtw, pm, Cw);
  gemm128<true, false, 64><<<dim3(M_TOK / 128, D_MODEL / 64, 1), 256, 0, stream>>>(
      Cw, Wt + 3 * WMAT, bo, bo, bo, d_out, nullptr, nullptr);
}

// Round 4
// 206.983 us; speedup vs baseline: 1.0803x; 1.0044x over previous
//
#include <hip/hip_runtime.h>
#include <hip/hip_bf16.h>
#include <stdint.h>
#include <math.h>

// Problem constants
#define D_MODEL 1024
#define NHEAD   16
#define DHEAD   64
#define BATCH   2
#define SEQ     2048
#define M_TOK   (BATCH * SEQ)   // 4096 tokens

// Q pre-scale: 1/sqrt(DHEAD) * log2(e), folded into the Q projection so the
// QK^T MFMA result is directly the exp2 argument.
#define QSCALE 0.18033688011112042f

typedef __attribute__((ext_vector_type(8))) short   short8;
typedef __attribute__((ext_vector_type(8))) __bf16  bf16x8;
typedef __attribute__((ext_vector_type(4))) float   f32x4;

__device__ inline short f2bf(float f) {           // RNE
  unsigned int u = __builtin_bit_cast(unsigned int, f);
  unsigned int r = (u + 0x7FFFu + ((u >> 16) & 1u)) >> 16;
  return (short)(unsigned short)r;
}
__device__ inline short f2bf_fast(float f) {      // round-nearest (ties away), 2 ops
  unsigned int u = __builtin_bit_cast(unsigned int, f);
  return (short)(unsigned short)((u + 0x8000u) >> 16);
}

// async global -> LDS, 16B per lane. LDS dest must be wave-uniform base + lane*16.
__device__ inline void gl_lds16(const void* g, void* l) {
  __builtin_amdgcn_global_load_lds((__attribute__((address_space(1))) void*)(g),
                                   (__attribute__((address_space(3))) void*)(l),
                                   16, 0, 0);
}

__device__ inline bf16x8 lds_frag(const short* p) {
  return *(const bf16x8*)(p);
}

// ---------------------------------------------------------------------------
// Prep kernel (fused): z=0..3 -> transpose+convert weight matrix z
// (W[k][n] fp32 -> Wt[n][k] bf16); z=4 -> convert x fp32 -> bf16.
// Grid (16,16,5), 256 threads. One launch instead of two.
// ---------------------------------------------------------------------------
__global__ __launch_bounds__(256) void prep(const float* __restrict__ x,
                                            short* __restrict__ xb,
                                            const float* __restrict__ w0,
                                            const float* __restrict__ w1,
                                            const float* __restrict__ w2,
                                            const float* __restrict__ w3,
                                            short* __restrict__ out) {
  const int t = threadIdx.x;
  if (blockIdx.z == 4) {
    // convert x: 256 blocks (by*16+bx), 16384 elems each
    size_t base = ((size_t)blockIdx.y * 16 + blockIdx.x) * 16384;
    const float* in = x + base;
    short* o = xb + base;
#pragma unroll
    for (int i = 0; i < 16; ++i) {
      f32x4 v = *(const f32x4*)(in + (size_t)t * 4 + i * 1024);
      short4 s4;
      s4.x = f2bf(v[0]); s4.y = f2bf(v[1]); s4.z = f2bf(v[2]); s4.w = f2bf(v[3]);
      *(short4*)(o + (size_t)t * 4 + i * 1024) = s4;
    }
    return;
  }
  __shared__ short tile[64][72];
  const float* W = blockIdx.z == 0 ? w0 : blockIdx.z == 1 ? w1 : blockIdx.z == 2 ? w2 : w3;
  short* O = out + (size_t)blockIdx.z * (D_MODEL * (size_t)D_MODEL);
  int n0 = blockIdx.x * 64, k0 = blockIdx.y * 64;
#pragma unroll
  for (int i = 0; i < 16; ++i) {
    int idx = t + 256 * i;
    int r = idx >> 6, c = idx & 63;
    tile[r][c] = f2bf(W[(size_t)(k0 + r) * D_MODEL + n0 + c]);
  }
  __syncthreads();
#pragma unroll
  for (int i = 0; i < 16; ++i) {
    int idx = t + 256 * i;
    int r = idx >> 6, c = idx & 63;
    O[(size_t)(n0 + r) * D_MODEL + k0 + c] = tile[c][r];
  }
}

// ---------------------------------------------------------------------------
// GEMM: out[m][n] = A[m][k] * Bt[n][k]^T + bias[n]  (bf16 in, fp32 acc)
// 128xTN tile, BK=64, 256 threads (4 waves, 64x(TN/2) per wave).
// LDS XOR-chunk swizzled. TN=128 for QKV (768 blocks), TN=64 for the output
// projection (512 blocks = 2/CU). [R8 best-measured configuration]
// QKV launch (VT=true): z=0 -> Q scaled by QSCALE; z=2 -> V written transposed
// with MASKED KEY ROWS ZEROED (pm[b][s]==1 -> 0) and the key axis PERMUTED
// within each 32-key block (p = bitshuffle(key)) so the attention PV step can
// read V fragments as single floor-pattern b128s (R3: the unpermuted layout
// forced b64 pairs -> 4.27M bank-conflict cycles).
// ---------------------------------------------------------------------------
template <bool OUTF32, bool VT, int TN>
__global__ __launch_bounds__(256) void gemm128(const short* __restrict__ A,
                                               const short* __restrict__ Bt_base,
                                               const float* __restrict__ b0,
                                               const float* __restrict__ b1,
                                               const float* __restrict__ b2,
                                               void* __restrict__ out_base,
                                               short* __restrict__ vt,
                                               const int* __restrict__ pm) {
  constexpr int NI = TN / 32;      // per-wave n-subtiles (4 or 2)
  const int z = blockIdx.z;
  const short* Bt   = Bt_base + (size_t)z * (D_MODEL * (size_t)D_MODEL);
  const float* bias = (z == 0) ? b0 : (z == 1) ? b1 : b2;

  __shared__ short As[128 * 64];   // [row][k] 64-wide rows, swizzled
  __shared__ short Bs[TN * 64];    // [n][k], swizzled

  const int t = threadIdx.x;
  const int lane = t & 63;
  const int wid = t >> 6;
  const int wm = (wid >> 1) * 64, wn = (wid & 1) * (TN / 2);
  const int m0 = blockIdx.x * 128, n0 = blockIdx.y * TN;
  const int cl = lane & 15, q = lane >> 4;
  const int sw = cl & 7;

  f32x4 acc[4][NI];
#pragma unroll
  for (int i = 0; i < 4; ++i)
#pragma unroll
    for (int j = 0; j < NI; ++j) acc[i][j] = 0.0f;

  for (int k0 = 0; k0 < D_MODEL; k0 += 64) {
    __syncthreads();
#pragma unroll
    for (int i = 0; i < 4; ++i) {   // A: 1024 chunks
      int c = t + 256 * i;
      int row = c >> 3, cp = c & 7;
      int col = ((cp ^ (row & 7)) * 8);
      gl_lds16(A + (size_t)(m0 + row) * D_MODEL + k0 + col, (void*)(As + c * 8));
    }
#pragma unroll
    for (int i = 0; i < NI; ++i) {  // B: TN*8 chunks
      int c = t + 256 * i;
      int row = c >> 3, cp = c & 7;
      int col = ((cp ^ (row & 7)) * 8);
      gl_lds16(Bt + (size_t)(n0 + row) * D_MODEL + k0 + col, (void*)(Bs + c * 8));
    }
    __syncthreads();

    bf16x8 af[4][2], bfr[NI][2];
#pragma unroll
    for (int mi = 0; mi < 4; ++mi) {
      af[mi][0] = lds_frag(As + (wm + mi * 16 + cl) * 64 + (q ^ sw) * 8);
      af[mi][1] = lds_frag(As + (wm + mi * 16 + cl) * 64 + ((4 + q) ^ sw) * 8);
    }
#pragma unroll
    for (int ni = 0; ni < NI; ++ni) {
      bfr[ni][0] = lds_frag(Bs + (wn + ni * 16 + cl) * 64 + (q ^ sw) * 8);
      bfr[ni][1] = lds_frag(Bs + (wn + ni * 16 + cl) * 64 + ((4 + q) ^ sw) * 8);
    }
#pragma unroll
    for (int mi = 0; mi < 4; ++mi)
#pragma unroll
      for (int ni = 0; ni < NI; ++ni) {
        acc[mi][ni] = __builtin_amdgcn_mfma_f32_16x16x32_bf16(af[mi][0], bfr[ni][0], acc[mi][ni], 0, 0, 0);
        acc[mi][ni] = __builtin_amdgcn_mfma_f32_16x16x32_bf16(af[mi][1], bfr[ni][1], acc[mi][ni], 0, 0, 0);
      }
  }

  // Epilogue: C/D layout col=lane&15, row=(lane>>4)*4+reg
  const float oscale = (VT && z == 0) ? QSCALE : 1.0f;
  int4 mm[4];
  if (VT && z == 2) {
#pragma unroll
    for (int mi = 0; mi < 4; ++mi) {
      int rbase = m0 + wm + mi * 16 + q * 4;
      mm[mi] = *(const int4*)(pm + (size_t)(rbase >> 11) * SEQ + (rbase & (SEQ - 1)));
    }
  }
#pragma unroll
  for (int ni = 0; ni < NI; ++ni) {
    int col = n0 + wn + ni * 16 + cl;
    float bv = bias[col];
#pragma unroll
    for (int mi = 0; mi < 4; ++mi) {
      int rbase = m0 + wm + mi * 16 + q * 4;
      if (VT && z == 2) {
        short4 o4;
        o4.x = (mm[mi].x == 1) ? (short)0 : f2bf_fast(acc[mi][ni][0] + bv);
        o4.y = (mm[mi].y == 1) ? (short)0 : f2bf_fast(acc[mi][ni][1] + bv);
        o4.z = (mm[mi].z == 1) ? (short)0 : f2bf_fast(acc[mi][ni][2] + bv);
        o4.w = (mm[mi].w == 1) ? (short)0 : f2bf_fast(acc[mi][ni][3] + bv);
        int btok = rbase >> 11;           // token block -> batch
        int s    = rbase & (SEQ - 1);
        // key-axis permutation within each 32-key block: storage p holds key
        // with bits rearranged (p[4:3]=key[3:2], p[2]=key[4], p[1:0]=key[1:0])
        // -> attn PV reads become contiguous b128 fragments. s is 4-aligned so
        // the short4 store stays contiguous.
        int sp = (s & ~31) | ((s & 16) >> 2) | ((s & 12) << 1) | (s & 3);
        *(short4*)(vt + (size_t)btok * ((size_t)D_MODEL * SEQ) + (size_t)col * SEQ + sp) = o4;
      } else {
#pragma unroll
        for (int r = 0; r < 4; ++r) {
          float v = (acc[mi][ni][r] + bv) * oscale;
          size_t idx = (size_t)(rbase + r) * D_MODEL + col;
          if (OUTF32) {
            ((float*)out_base)[idx] = v;
          } else {
            short* out = (short*)out_base + (size_t)z * ((size_t)M_TOK * D_MODEL);
            out[idx] = f2bf_fast(v);
          }
        }
      }
    }
  }
}

// ---------------------------------------------------------------------------
// Flash attention v8: v7 (in-register P, no LDS P slab) + permuted-V layout
// so PV's V fragments are single b128 reads at the floor bank pattern.
// R3 counters: v7's b64 V-read pattern cost 4.27M bank-conflict cycles (~10%
// of kernel) and regressed 62.8->68us despite removing the P round-trip.
// v8: Vtw's key axis is bit-shuffled per 32-key block (GEMM epilogue), making
// lane (cl,q) frag c's 8 keys {32c+4q+r, 32c+16+4q+r} contiguous in storage
// at chunk 4c+q -> read = lds_frag at ((4c+q)^sw)*8, same proven pattern as
// the K fragments. pf packing / u-mask / epilogue unchanged from v7.
// ---------------------------------------------------------------------------
__global__ __launch_bounds__(512) void attn_flash(const short* __restrict__ Q,
                                                  const short* __restrict__ K,
                                                  const short* __restrict__ Vt,
                                                  const int*   __restrict__ mask,
                                                  short* __restrict__ ctx) {
  const int qb = blockIdx.x;   // 0..15
  const int h  = blockIdx.y;   // 0..15
  const int b  = blockIdx.z;   // 0..1

  // layout (shorts): Qs[8192] | Ks[8192] | Vts[8192] | Usf(f32 2048 = 4096)
  // epilogue overlay: redO f32[8192] over Qs+Ks (32KB), redL f32 over Vts.
  __shared__ __align__(16) short smem[28672];
  short* Qs  = smem;
  short* Ks  = smem + 8192;
  short* Vts = smem + 16384;
  float* Usf = (float*)(smem + 24576);

  const int t = threadIdx.x;
  const int lane = t & 63;
  const int wid = t >> 6;           // 0..7
  const int wg  = wid >> 1;         // row-group 0..3 (32 q-rows each)
  const int kvh = wid & 1;          // kv half: keys [kvh*1024, kvh*1024+1024)
  const int cl = lane & 15, q = lane >> 4;
  const int sw = cl & 7;

  const size_t rowQ0 = (size_t)b * SEQ + (size_t)qb * 128;
  const size_t rowK0 = (size_t)b * SEQ;
  const size_t vbase = ((size_t)b * D_MODEL + h * DHEAD) * SEQ;

  // per-thread staging addresses (thread t owns LDS chunk t*16B; global
  // source pre-swizzled so LDS reads can XOR-deswizzle)
  const int srow = t >> 3, scp = t & 7;
  const int scol = (scp ^ (srow & 7)) * 8;
  const short* Kg0 = K + (rowK0 + srow) * D_MODEL + h * DHEAD + scol;
  const short* Kg1 = K + (rowK0 + 1024 + srow) * D_MODEL + h * DHEAD + scol;
  const short* Vg0 = Vt + vbase + (size_t)srow * SEQ + scol;
  const short* Vg1 = Vt + vbase + (size_t)srow * SEQ + 1024 + scol;

  // prologue: issue tile-0 K/V prefetch (lands during Q staging)
  short8 gk0 = *(const short8*)(Kg0);
  short8 gk1 = *(const short8*)(Kg1);
  short8 gv0 = *(const short8*)(Vg0);
  short8 gv1 = *(const short8*)(Vg1);

  // mask -> u f32 vector for the whole sequence (once, coalesced)
  {
    int4 mv = *(const int4*)(mask + (size_t)b * SEQ + t * 4);
    f32x4 u4;
    u4[0] = (mv.x == 1) ? 0.0f : 1.0f;
    u4[1] = (mv.y == 1) ? 0.0f : 1.0f;
    u4[2] = (mv.z == 1) ? 0.0f : 1.0f;
    u4[3] = (mv.w == 1) ? 0.0f : 1.0f;
    *(f32x4*)(Usf + t * 4) = u4;
  }

  // stage Q tile (128 rows x 64 d), swizzled
#pragma unroll
  for (int i = 0; i < 2; ++i) {
    int c = t + 512 * i;
    int row = c >> 3, cp = c & 7;
    gl_lds16(Q + (rowQ0 + row) * D_MODEL + h * DHEAD + ((cp ^ (row & 7)) * 8),
             (void*)(Qs + c * 8));
  }
  __syncthreads();

  // Register-resident Q fragments: wave owns rows [32*wg, 32*wg+32)
  bf16x8 qf[2][2];
#pragma unroll
  for (int rb = 0; rb < 2; ++rb) {
    int row = wg * 32 + rb * 16 + cl;
    qf[rb][0] = lds_frag(Qs + row * 64 + (q ^ sw) * 8);
    qf[rb][1] = lds_frag(Qs + row * 64 + ((4 + q) ^ sw) * 8);
  }
  const short* Kp = Ks  + kvh * 4096;
  const short* Vp = Vts + kvh * 4096;
  const float* Up = Usf + kvh * 1024;

  f32x4 lacc[2], oacc[2][4];
#pragma unroll
  for (int rb = 0; rb < 2; ++rb) {
    lacc[rb] = 0.0f;
#pragma unroll
    for (int dj = 0; dj < 4; ++dj) oacc[rb][dj] = 0.0f;
  }

  for (int s0 = 0; s0 < 1024; s0 += 64) {
    __syncthreads();   // prior tile's LDS reads done (also orders Qs/Usf init)

    // write the prefetched K/V regs into the (single-buffered) LDS tiles
    *(short8*)(Ks  + t * 8)        = gk0;
    *(short8*)(Ks  + 4096 + t * 8) = gk1;
    *(short8*)(Vts + t * 8)        = gv0;
    *(short8*)(Vts + 4096 + t * 8) = gv1;
    __syncthreads();

    // issue next tile's prefetch; latency hides under this tile's compute
    if (s0 + 64 < 1024) {
      int sn = s0 + 64;
      gk0 = *(const short8*)(Kg0 + (size_t)sn * D_MODEL);
      gk1 = *(const short8*)(Kg1 + (size_t)sn * D_MODEL);
      gv0 = *(const short8*)(Vg0 + sn);
      gv1 = *(const short8*)(Vg1 + sn);
    }

    // S^T = K Q^T via mfma(kf, qf): C row = key 4g+r (tile j), col = q-row cl
    f32x4 s[2][4];
#pragma unroll
    for (int j = 0; j < 4; ++j) {
      bf16x8 kf0 = lds_frag(Kp + (j * 16 + cl) * 64 + (q ^ sw) * 8);
      bf16x8 kf1 = lds_frag(Kp + (j * 16 + cl) * 64 + ((4 + q) ^ sw) * 8);
#pragma unroll
      for (int rb = 0; rb < 2; ++rb) {
        f32x4 sa = 0.0f;
        sa = __builtin_amdgcn_mfma_f32_16x16x32_bf16(kf0, qf[rb][0], sa, 0, 0, 0);
        sa = __builtin_amdgcn_mfma_f32_16x16x32_bf16(kf1, qf[rb][1], sa, 0, 0, 0);
        s[rb][j] = sa;
      }
    }

    // p = u * exp2(s) in registers; l accumulates as f32x4
    f32x4 uv[4];
#pragma unroll
    for (int j = 0; j < 4; ++j)
      uv[j] = *(const f32x4*)(Up + s0 + j * 16 + 4 * q);   // broadcast across cl
#pragma unroll
    for (int rb = 0; rb < 2; ++rb)
#pragma unroll
      for (int j = 0; j < 4; ++j) {
#pragma unroll
        for (int r = 0; r < 4; ++r)
          s[rb][j][r] = __builtin_amdgcn_exp2f(s[rb][j][r]) * uv[j][r];
        lacc[rb] += s[rb][j];
      }

    // pack P to bf16 lane-locally: pf[c] = keys {32c+4g+r} ++ {32c+16+4g+r}
    bf16x8 pf[2][2];
#pragma unroll
    for (int rb = 0; rb < 2; ++rb)
#pragma unroll
      for (int c = 0; c < 2; ++c) {
        bf16x8 v;
        v[0] = (__bf16)s[rb][2 * c][0];
        v[1] = (__bf16)s[rb][2 * c][1];
        v[2] = (__bf16)s[rb][2 * c][2];
        v[3] = (__bf16)s[rb][2 * c][3];
        v[4] = (__bf16)s[rb][2 * c + 1][0];
        v[5] = (__bf16)s[rb][2 * c + 1][1];
        v[6] = (__bf16)s[rb][2 * c + 1][2];
        v[7] = (__bf16)s[rb][2 * c + 1][3];
        pf[rb][c] = v;
      }

    // O^T += V^T P^T. With the permuted-V storage, lane (cl,q) frag c's 8
    // k-slot elements are storage-contiguous at chunk 4c+q -> single b128
    // at ((4c+q)^sw)*8: same floor bank pattern as the K fragments.
#pragma unroll
    for (int dj = 0; dj < 4; ++dj) {
      const short* vrow = Vp + (dj * 16 + cl) * 64;
#pragma unroll
      for (int c = 0; c < 2; ++c) {
        bf16x8 vfc = lds_frag(vrow + (((4 * c + q) ^ sw) * 8));
#pragma unroll
        for (int rb = 0; rb < 2; ++rb)
          oacc[rb][dj] = __builtin_amdgcn_mfma_f32_16x16x32_bf16(vfc, pf[rb][c], oacc[rb][dj], 0, 0, 0);
      }
    }
  }

  // ---- combine kv-halves through LDS (O,l are linear in the key axis) ----
  __syncthreads();                       // all compute reads of LDS done
  float hl[2];
#pragma unroll
  for (int rb = 0; rb < 2; ++rb)
    hl[rb] = lacc[rb][0] + lacc[rb][1] + lacc[rb][2] + lacc[rb][3];

  float* redO = (float*)smem;            // 32 KB (Qs+Ks region)
  float* redL = (float*)(smem + 16384);  // 2 KB (start of Vts region)
  const int slot = wg * 64 + lane;
  if (kvh) {
#pragma unroll
    for (int rb = 0; rb < 2; ++rb) {
#pragma unroll
      for (int dj = 0; dj < 4; ++dj) {
        int qi = (rb * 4 + dj) ^ (lane & 7);   // XOR-swizzle: spread banks
        *(f32x4*)(redO + slot * 32 + qi * 4) = oacc[rb][dj];
      }
      redL[slot * 2 + rb] = hl[rb];
    }
  }
  __syncthreads();
  if (kvh) return;
#pragma unroll
  for (int rb = 0; rb < 2; ++rb) {
    hl[rb] += redL[slot * 2 + rb];
#pragma unroll
    for (int dj = 0; dj < 4; ++dj) {
      int qi = (rb * 4 + dj) ^ (lane & 7);
      oacc[rb][dj] += *(const f32x4*)(redO + slot * 32 + qi * 4);
    }
  }
  // l: sum over the 4 g-lane groups (lanes ^16, ^32 share the same cl)
#pragma unroll
  for (int rb = 0; rb < 2; ++rb) {
    hl[rb] += __shfl_xor(hl[rb], 16);
    hl[rb] += __shfl_xor(hl[rb], 32);
  }

  // finalize: O^T layout -> lane (cl,g) reg r holds O[q=wg*32+rb*16+cl]
  // [d = dj*16 + 4g + r]; 4 consecutive d per reg -> short4 stores.
#pragma unroll
  for (int rb = 0; rb < 2; ++rb) {
    float inv = (hl[rb] > 0.0f) ? 1.0f / hl[rb] : 0.0f;
    size_t row = rowQ0 + wg * 32 + rb * 16 + cl;
#pragma unroll
    for (int dj = 0; dj < 4; ++dj) {
      short4 o4;
      o4.x = f2bf(oacc[rb][dj][0] * inv);
      o4.y = f2bf(oacc[rb][dj][1] * inv);
      o4.z = f2bf(oacc[rb][dj][2] * inv);
      o4.w = f2bf(oacc[rb][dj][3] * inv);
      *(short4*)(ctx + row * D_MODEL + h * DHEAD + dj * 16 + q * 4) = o4;
    }
  }
}

// ---------------------------------------------------------------------------
extern "C" void kernel_launch(void* const* d_in, const int* in_sizes, int n_in,
                              void* d_out, int out_size, void* d_ws, size_t ws_size,
                              hipStream_t stream) {
  (void)in_sizes; (void)n_in; (void)out_size; (void)ws_size;

  const float* x  = (const float*)d_in[0];
  const int*   pm = (const int*)  d_in[1];
  const float* Wq = (const float*)d_in[2];
  const float* bq = (const float*)d_in[3];
  const float* Wk = (const float*)d_in[4];
  const float* bk = (const float*)d_in[5];
  const float* Wv = (const float*)d_in[6];
  const float* bv = (const float*)d_in[7];
  const float* Wo = (const float*)d_in[8];
  const float* bo = (const float*)d_in[9];

  const size_t WMAT = (size_t)D_MODEL * D_MODEL;   // 1M elems
  const size_t TOKD = (size_t)M_TOK * D_MODEL;     // 4M elems

  short* base = (short*)d_ws;
  short* Wt = base;              // 4 transposed bf16 weights: 8 MB
  short* xb = base + 4 * WMAT;   // bf16 x: 8 MB
  short* Qw = xb + TOKD;         // 8 MB (z=0, pre-scaled by QSCALE)
  short* Kw = Qw + TOKD;         // 8 MB (z=1)
  short* Vtw = Kw + TOKD;        // 8 MB Vt[b][n][s], masked rows zeroed, key-permuted
  short* Cw = Vtw + TOKD;        // 8 MB  (total 48 MB of ws)

  prep<<<dim3(16, 16, 5), 256, 0, stream>>>(x, xb, Wq, Wk, Wv, Wo, Wt);
  gemm128<false, true, 128><<<dim3(M_TOK / 128, D_MODEL / 128, 3), 256, 0, stream>>>(
      xb, Wt, bq, bk, bv, Qw, Vtw, pm);
  attn_flash<<<dim3(SEQ / 128, NHEAD, BATCH), 512, 0, stream>>>(Qw, Kw, Vtw, pm, Cw);
  gemm128<true, false, 64><<<dim3(M_TOK / 128, D_MODEL / 64, 1), 256, 0, stream>>>(
      Cw, Wt + 3 * WMAT, bo, bo, bo, d_out, nullptr, nullptr);
}

// Round 5
// 192.735 us; speedup vs baseline: 1.1602x; 1.0739x over previous
//
#include <hip/hip_runtime.h>
#include <hip/hip_bf16.h>
#include <stdint.h>
#include <math.h>

// Problem constants
#define D_MODEL 1024
#define NHEAD   16
#define DHEAD   64
#define BATCH   2
#define SEQ     2048
#define M_TOK   (BATCH * SEQ)   // 4096 tokens

// Q pre-scale: 1/sqrt(DHEAD) * log2(e), folded into the Q projection so the
// QK^T MFMA result is directly the exp2 argument.
#define QSCALE 0.18033688011112042f

typedef __attribute__((ext_vector_type(8))) short   short8;
typedef __attribute__((ext_vector_type(8))) __bf16  bf16x8;
typedef __attribute__((ext_vector_type(4))) float   f32x4;

__device__ inline short f2bf(float f) {           // RNE
  unsigned int u = __builtin_bit_cast(unsigned int, f);
  unsigned int r = (u + 0x7FFFu + ((u >> 16) & 1u)) >> 16;
  return (short)(unsigned short)r;
}
__device__ inline short f2bf_fast(float f) {      // round-nearest (ties away), 2 ops
  unsigned int u = __builtin_bit_cast(unsigned int, f);
  return (short)(unsigned short)((u + 0x8000u) >> 16);
}

// async global -> LDS, 16B per lane. LDS dest must be wave-uniform base + lane*16.
__device__ inline void gl_lds16(const void* g, void* l) {
  __builtin_amdgcn_global_load_lds((__attribute__((address_space(1))) void*)(g),
                                   (__attribute__((address_space(3))) void*)(l),
                                   16, 0, 0);
}

__device__ inline bf16x8 lds_frag(const short* p) {
  return *(const bf16x8*)(p);
}

// ---------------------------------------------------------------------------
// Prep kernel (fused): z=0..3 -> transpose+convert weight matrix z
// (W[k][n] fp32 -> Wt[n][k] bf16); z=4 -> convert x fp32 -> bf16.
// Grid (16,16,5), 256 threads. One launch instead of two.
// ---------------------------------------------------------------------------
__global__ __launch_bounds__(256) void prep(const float* __restrict__ x,
                                            short* __restrict__ xb,
                                            const float* __restrict__ w0,
                                            const float* __restrict__ w1,
                                            const float* __restrict__ w2,
                                            const float* __restrict__ w3,
                                            short* __restrict__ out) {
  const int t = threadIdx.x;
  if (blockIdx.z == 4) {
    // convert x: 256 blocks (by*16+bx), 16384 elems each
    size_t base = ((size_t)blockIdx.y * 16 + blockIdx.x) * 16384;
    const float* in = x + base;
    short* o = xb + base;
#pragma unroll
    for (int i = 0; i < 16; ++i) {
      f32x4 v = *(const f32x4*)(in + (size_t)t * 4 + i * 1024);
      short4 s4;
      s4.x = f2bf(v[0]); s4.y = f2bf(v[1]); s4.z = f2bf(v[2]); s4.w = f2bf(v[3]);
      *(short4*)(o + (size_t)t * 4 + i * 1024) = s4;
    }
    return;
  }
  __shared__ short tile[64][72];
  const float* W = blockIdx.z == 0 ? w0 : blockIdx.z == 1 ? w1 : blockIdx.z == 2 ? w2 : w3;
  short* O = out + (size_t)blockIdx.z * (D_MODEL * (size_t)D_MODEL);
  int n0 = blockIdx.x * 64, k0 = blockIdx.y * 64;
#pragma unroll
  for (int i = 0; i < 16; ++i) {
    int idx = t + 256 * i;
    int r = idx >> 6, c = idx & 63;
    tile[r][c] = f2bf(W[(size_t)(k0 + r) * D_MODEL + n0 + c]);
  }
  __syncthreads();
#pragma unroll
  for (int i = 0; i < 16; ++i) {
    int idx = t + 256 * i;
    int r = idx >> 6, c = idx & 63;
    O[(size_t)(n0 + r) * D_MODEL + k0 + c] = tile[c][r];
  }
}

// ---------------------------------------------------------------------------
// GEMM: out[m][n] = A[m][k] * Bt[n][k]^T + bias[n]  (bf16 in, fp32 acc)
// 128xTN tile, BK=64, 256 threads (4 waves, 64x(TN/2) per wave).
// LDS XOR-chunk swizzled. TN=128 for QKV (768 blocks), TN=64 for the output
// projection (512 blocks = 2/CU). [R8 best-measured configuration]
// QKV launch (VT=true): z=0 -> Q scaled by QSCALE; z=2 -> V written transposed
// with MASKED KEY ROWS ZEROED (pm[b][s]==1 -> 0) and the key axis PERMUTED
// within each 32-key block (p = bitshuffle(key)) so the attention PV step can
// read V fragments as single floor-pattern b128s (R3: the unpermuted layout
// forced b64 pairs -> 4.27M bank-conflict cycles; R4: permuted layout dropped
// them to 74K).
// ---------------------------------------------------------------------------
template <bool OUTF32, bool VT, int TN>
__global__ __launch_bounds__(256) void gemm128(const short* __restrict__ A,
                                               const short* __restrict__ Bt_base,
                                               const float* __restrict__ b0,
                                               const float* __restrict__ b1,
                                               const float* __restrict__ b2,
                                               void* __restrict__ out_base,
                                               short* __restrict__ vt,
                                               const int* __restrict__ pm) {
  constexpr int NI = TN / 32;      // per-wave n-subtiles (4 or 2)
  const int z = blockIdx.z;
  const short* Bt   = Bt_base + (size_t)z * (D_MODEL * (size_t)D_MODEL);
  const float* bias = (z == 0) ? b0 : (z == 1) ? b1 : b2;

  __shared__ short As[128 * 64];   // [row][k] 64-wide rows, swizzled
  __shared__ short Bs[TN * 64];    // [n][k], swizzled

  const int t = threadIdx.x;
  const int lane = t & 63;
  const int wid = t >> 6;
  const int wm = (wid >> 1) * 64, wn = (wid & 1) * (TN / 2);
  const int m0 = blockIdx.x * 128, n0 = blockIdx.y * TN;
  const int cl = lane & 15, q = lane >> 4;
  const int sw = cl & 7;

  f32x4 acc[4][NI];
#pragma unroll
  for (int i = 0; i < 4; ++i)
#pragma unroll
    for (int j = 0; j < NI; ++j) acc[i][j] = 0.0f;

  for (int k0 = 0; k0 < D_MODEL; k0 += 64) {
    __syncthreads();
#pragma unroll
    for (int i = 0; i < 4; ++i) {   // A: 1024 chunks
      int c = t + 256 * i;
      int row = c >> 3, cp = c & 7;
      int col = ((cp ^ (row & 7)) * 8);
      gl_lds16(A + (size_t)(m0 + row) * D_MODEL + k0 + col, (void*)(As + c * 8));
    }
#pragma unroll
    for (int i = 0; i < NI; ++i) {  // B: TN*8 chunks
      int c = t + 256 * i;
      int row = c >> 3, cp = c & 7;
      int col = ((cp ^ (row & 7)) * 8);
      gl_lds16(Bt + (size_t)(n0 + row) * D_MODEL + k0 + col, (void*)(Bs + c * 8));
    }
    __syncthreads();

    bf16x8 af[4][2], bfr[NI][2];
#pragma unroll
    for (int mi = 0; mi < 4; ++mi) {
      af[mi][0] = lds_frag(As + (wm + mi * 16 + cl) * 64 + (q ^ sw) * 8);
      af[mi][1] = lds_frag(As + (wm + mi * 16 + cl) * 64 + ((4 + q) ^ sw) * 8);
    }
#pragma unroll
    for (int ni = 0; ni < NI; ++ni) {
      bfr[ni][0] = lds_frag(Bs + (wn + ni * 16 + cl) * 64 + (q ^ sw) * 8);
      bfr[ni][1] = lds_frag(Bs + (wn + ni * 16 + cl) * 64 + ((4 + q) ^ sw) * 8);
    }
#pragma unroll
    for (int mi = 0; mi < 4; ++mi)
#pragma unroll
      for (int ni = 0; ni < NI; ++ni) {
        acc[mi][ni] = __builtin_amdgcn_mfma_f32_16x16x32_bf16(af[mi][0], bfr[ni][0], acc[mi][ni], 0, 0, 0);
        acc[mi][ni] = __builtin_amdgcn_mfma_f32_16x16x32_bf16(af[mi][1], bfr[ni][1], acc[mi][ni], 0, 0, 0);
      }
  }

  // Epilogue: C/D layout col=lane&15, row=(lane>>4)*4+reg
  const float oscale = (VT && z == 0) ? QSCALE : 1.0f;
  int4 mm[4];
  if (VT && z == 2) {
#pragma unroll
    for (int mi = 0; mi < 4; ++mi) {
      int rbase = m0 + wm + mi * 16 + q * 4;
      mm[mi] = *(const int4*)(pm + (size_t)(rbase >> 11) * SEQ + (rbase & (SEQ - 1)));
    }
  }
#pragma unroll
  for (int ni = 0; ni < NI; ++ni) {
    int col = n0 + wn + ni * 16 + cl;
    float bv = bias[col];
#pragma unroll
    for (int mi = 0; mi < 4; ++mi) {
      int rbase = m0 + wm + mi * 16 + q * 4;
      if (VT && z == 2) {
        short4 o4;
        o4.x = (mm[mi].x == 1) ? (short)0 : f2bf_fast(acc[mi][ni][0] + bv);
        o4.y = (mm[mi].y == 1) ? (short)0 : f2bf_fast(acc[mi][ni][1] + bv);
        o4.z = (mm[mi].z == 1) ? (short)0 : f2bf_fast(acc[mi][ni][2] + bv);
        o4.w = (mm[mi].w == 1) ? (short)0 : f2bf_fast(acc[mi][ni][3] + bv);
        int btok = rbase >> 11;           // token block -> batch
        int s    = rbase & (SEQ - 1);
        // key-axis permutation within each 32-key block: storage p holds key
        // with bits rearranged (p[4:3]=key[3:2], p[2]=key[4], p[1:0]=key[1:0])
        // -> attn PV reads become contiguous b128 fragments. s is 4-aligned so
        // the short4 store stays contiguous.
        int sp = (s & ~31) | ((s & 16) >> 2) | ((s & 12) << 1) | (s & 3);
        *(short4*)(vt + (size_t)btok * ((size_t)D_MODEL * SEQ) + (size_t)col * SEQ + sp) = o4;
      } else {
#pragma unroll
        for (int r = 0; r < 4; ++r) {
          float v = (acc[mi][ni][r] + bv) * oscale;
          size_t idx = (size_t)(rbase + r) * D_MODEL + col;
          if (OUTF32) {
            ((float*)out_base)[idx] = v;
          } else {
            short* out = (short*)out_base + (size_t)z * ((size_t)M_TOK * D_MODEL);
            out[idx] = f2bf_fast(v);
          }
        }
      }
    }
  }
}

// ---------------------------------------------------------------------------
// Flash attention v9: v8 (in-register P, permuted-V b128 frags) +
// double-buffered gl_lds K/V staging + additive-mask C-init.
// R4 counters: conflicts fixed (74K) but 60.6us; LDS 47% / VALU 38% / MFMA 22%
// -> residual is the 2-barrier-per-tile staging convoy (pre-committed R3
// branch). v9 structure per tile: ONE __syncthreads; gl_lds DMA stages tile
// t+1 into the ping-pong buffer right after the barrier, landing during tile
// t's full compute phase (~600cy >> L2 latency) so the next barrier's vmcnt
// drain is free. No wave-issued ds_writes, no staging registers.
// LDS 72KB (bufA 32K | bufB 32K, Q staged into bufB prologue-only | bias 8K),
// still 2 blocks/CU. Mask folded in as C-init bias (0 / -1e30: exp2 -> exact
// 0), removing the 32 u-multiplies per wave per tile.
// ---------------------------------------------------------------------------
__global__ __launch_bounds__(512) void attn_flash(const short* __restrict__ Q,
                                                  const short* __restrict__ K,
                                                  const short* __restrict__ Vt,
                                                  const int*   __restrict__ mask,
                                                  short* __restrict__ ctx) {
  const int qb = blockIdx.x;   // 0..15
  const int h  = blockIdx.y;   // 0..15
  const int b  = blockIdx.z;   // 0..1

  // shorts: bufA[16384] | bufB[16384] | Usf f32[2048] (additive bias)
  // bufX = K[2 halves][64key][64d] ++ Vt[2 halves][64d][64key], swizzled.
  // prologue: Q tile staged into bufB[0:8192]. epilogue: redO over bufA,
  // redL over bufB start.
  __shared__ __align__(16) short smem[36864];
  short* bufA = smem;
  short* bufB = smem + 16384;
  float* Usf  = (float*)(smem + 32768);

  const int t = threadIdx.x;
  const int lane = t & 63;
  const int wid = t >> 6;           // 0..7
  const int wg  = wid >> 1;         // row-group 0..3 (32 q-rows each)
  const int kvh = wid & 1;          // kv half: keys [kvh*1024, kvh*1024+1024)
  const int cl = lane & 15, q = lane >> 4;
  const int sw = cl & 7;

  const size_t rowQ0 = (size_t)b * SEQ + (size_t)qb * 128;
  const size_t rowK0 = (size_t)b * SEQ;
  const size_t vbase = ((size_t)b * D_MODEL + h * DHEAD) * SEQ;

  // per-thread staging addresses (thread t owns LDS chunk t*16B; global
  // source pre-swizzled so LDS reads can XOR-deswizzle)
  const int srow = t >> 3, scp = t & 7;
  const int scol = (scp ^ (srow & 7)) * 8;
  const short* Kg0 = K + (rowK0 + srow) * D_MODEL + h * DHEAD + scol;
  const short* Kg1 = K + (rowK0 + 1024 + srow) * D_MODEL + h * DHEAD + scol;
  const short* Vg0 = Vt + vbase + (size_t)srow * SEQ + scol;
  const short* Vg1 = Vt + vbase + (size_t)srow * SEQ + 1024 + scol;

  // DMA-stage one 128-key tile (64/half K + V) into buf. 4 chunks/thread.
  auto stage = [&](short* buf, int sn) {
    gl_lds16(Kg0 + (size_t)sn * D_MODEL, (void*)(buf + t * 8));
    gl_lds16(Kg1 + (size_t)sn * D_MODEL, (void*)(buf + 4096 + t * 8));
    gl_lds16(Vg0 + sn,                   (void*)(buf + 8192 + t * 8));
    gl_lds16(Vg1 + sn,                   (void*)(buf + 8192 + 4096 + t * 8));
  };

  // prologue: KV tile 0 -> bufA; Q tile -> bufB[0:8192]; mask bias -> Usf
  stage(bufA, 0);
#pragma unroll
  for (int i = 0; i < 2; ++i) {
    int c = t + 512 * i;
    int row = c >> 3, cp = c & 7;
    gl_lds16(Q + (rowQ0 + row) * D_MODEL + h * DHEAD + ((cp ^ (row & 7)) * 8),
             (void*)(bufB + c * 8));
  }
  {
    int4 mv = *(const int4*)(mask + (size_t)b * SEQ + t * 4);
    f32x4 u4;
    u4[0] = (mv.x == 1) ? -1e30f : 0.0f;
    u4[1] = (mv.y == 1) ? -1e30f : 0.0f;
    u4[2] = (mv.z == 1) ? -1e30f : 0.0f;
    u4[3] = (mv.w == 1) ? -1e30f : 0.0f;
    *(f32x4*)(Usf + t * 4) = u4;
  }
  __syncthreads();

  // Register-resident Q fragments: wave owns rows [32*wg, 32*wg+32)
  bf16x8 qf[2][2];
#pragma unroll
  for (int rb = 0; rb < 2; ++rb) {
    int row = wg * 32 + rb * 16 + cl;
    qf[rb][0] = lds_frag(bufB + row * 64 + (q ^ sw) * 8);
    qf[rb][1] = lds_frag(bufB + row * 64 + ((4 + q) ^ sw) * 8);
  }

  f32x4 lacc[2], oacc[2][4];
#pragma unroll
  for (int rb = 0; rb < 2; ++rb) {
    lacc[rb] = 0.0f;
#pragma unroll
    for (int dj = 0; dj < 4; ++dj) oacc[rb][dj] = 0.0f;
  }

  // one 128-key tile (64 keys from this wave's half)
  auto compute = [&](const short* buf, int s0) {
    const short* Kp = buf + kvh * 4096;
    const short* Vp = buf + 8192 + kvh * 4096;
    const float* Bp = Usf + kvh * 1024 + s0 + 4 * q;

    // S^T = K Q^T + bias (C-init): C row = key 4g+r (tile j), col = q-row cl
    f32x4 s[2][4];
#pragma unroll
    for (int j = 0; j < 4; ++j) {
      bf16x8 kf0 = lds_frag(Kp + (j * 16 + cl) * 64 + (q ^ sw) * 8);
      bf16x8 kf1 = lds_frag(Kp + (j * 16 + cl) * 64 + ((4 + q) ^ sw) * 8);
      f32x4 cv = *(const f32x4*)(Bp + j * 16);   // broadcast across cl
#pragma unroll
      for (int rb = 0; rb < 2; ++rb) {
        f32x4 sa = cv;
        sa = __builtin_amdgcn_mfma_f32_16x16x32_bf16(kf0, qf[rb][0], sa, 0, 0, 0);
        sa = __builtin_amdgcn_mfma_f32_16x16x32_bf16(kf1, qf[rb][1], sa, 0, 0, 0);
        s[rb][j] = sa;
      }
    }

    // p = exp2(s + bias) in registers (masked -> exact 0); l accumulates f32x4
#pragma unroll
    for (int rb = 0; rb < 2; ++rb)
#pragma unroll
      for (int j = 0; j < 4; ++j) {
#pragma unroll
        for (int r = 0; r < 4; ++r)
          s[rb][j][r] = __builtin_amdgcn_exp2f(s[rb][j][r]);
        lacc[rb] += s[rb][j];
      }

    // pack P to bf16 lane-locally: pf[c] = keys {32c+4g+r} ++ {32c+16+4g+r}
    bf16x8 pf[2][2];
#pragma unroll
    for (int rb = 0; rb < 2; ++rb)
#pragma unroll
      for (int c = 0; c < 2; ++c) {
        bf16x8 v;
        v[0] = (__bf16)s[rb][2 * c][0];
        v[1] = (__bf16)s[rb][2 * c][1];
        v[2] = (__bf16)s[rb][2 * c][2];
        v[3] = (__bf16)s[rb][2 * c][3];
        v[4] = (__bf16)s[rb][2 * c + 1][0];
        v[5] = (__bf16)s[rb][2 * c + 1][1];
        v[6] = (__bf16)s[rb][2 * c + 1][2];
        v[7] = (__bf16)s[rb][2 * c + 1][3];
        pf[rb][c] = v;
      }

    // O^T += V^T P^T. Permuted-V storage: lane (cl,q) frag c's 8 k-slot
    // elements are contiguous at chunk 4c+q -> single b128 (floor pattern).
#pragma unroll
    for (int dj = 0; dj < 4; ++dj) {
      const short* vrow = Vp + (dj * 16 + cl) * 64;
#pragma unroll
      for (int c = 0; c < 2; ++c) {
        bf16x8 vfc = lds_frag(vrow + (((4 * c + q) ^ sw) * 8));
#pragma unroll
        for (int rb = 0; rb < 2; ++rb)
          oacc[rb][dj] = __builtin_amdgcn_mfma_f32_16x16x32_bf16(vfc, pf[rb][c], oacc[rb][dj], 0, 0, 0);
      }
    }
  };

  // main loop: 8 iters x 2 ping-pong phases = 16 tiles of 128 keys.
  // Each phase: ONE barrier, then DMA-stage the next tile into the other
  // buffer (lands during this phase's compute), then compute.
  for (int it = 0; it < 8; ++it) {
    int s0 = it * 128;                 // half-space key offset
    __syncthreads();                   // drains bufA loads (issued last phase)
    stage(bufB, s0 + 64);              // overwrites Q region on it=0 (qf in regs)
    compute(bufA, s0);
    __syncthreads();                   // drains bufB loads
    if (it < 7) stage(bufA, s0 + 128);
    compute(bufB, s0 + 64);
  }

  // ---- combine kv-halves through LDS (O,l are linear in the key axis) ----
  __syncthreads();                       // all compute reads of LDS done
  float hl[2];
#pragma unroll
  for (int rb = 0; rb < 2; ++rb)
    hl[rb] = lacc[rb][0] + lacc[rb][1] + lacc[rb][2] + lacc[rb][3];

  float* redO = (float*)smem;            // 32 KB (bufA region)
  float* redL = (float*)(smem + 16384);  // 2 KB (bufB region)
  const int slot = wg * 64 + lane;
  if (kvh) {
#pragma unroll
    for (int rb = 0; rb < 2; ++rb) {
#pragma unroll
      for (int dj = 0; dj < 4; ++dj) {
        int qi = (rb * 4 + dj) ^ (lane & 7);   // XOR-swizzle: spread banks
        *(f32x4*)(redO + slot * 32 + qi * 4) = oacc[rb][dj];
      }
      redL[slot * 2 + rb] = hl[rb];
    }
  }
  __syncthreads();
  if (kvh) return;
#pragma unroll
  for (int rb = 0; rb < 2; ++rb) {
    hl[rb] += redL[slot * 2 + rb];
#pragma unroll
    for (int dj = 0; dj < 4; ++dj) {
      int qi = (rb * 4 + dj) ^ (lane & 7);
      oacc[rb][dj] += *(const f32x4*)(redO + slot * 32 + qi * 4);
    }
  }
  // l: sum over the 4 g-lane groups (lanes ^16, ^32 share the same cl)
#pragma unroll
  for (int rb = 0; rb < 2; ++rb) {
    hl[rb] += __shfl_xor(hl[rb], 16);
    hl[rb] += __shfl_xor(hl[rb], 32);
  }

  // finalize: O^T layout -> lane (cl,g) reg r holds O[q=wg*32+rb*16+cl]
  // [d = dj*16 + 4g + r]; 4 consecutive d per reg -> short4 stores.
#pragma unroll
  for (int rb = 0; rb < 2; ++rb) {
    float inv = (hl[rb] > 0.0f) ? 1.0f / hl[rb] : 0.0f;
    size_t row = rowQ0 + wg * 32 + rb * 16 + cl;
#pragma unroll
    for (int dj = 0; dj < 4; ++dj) {
      short4 o4;
      o4.x = f2bf(oacc[rb][dj][0] * inv);
      o4.y = f2bf(oacc[rb][dj][1] * inv);
      o4.z = f2bf(oacc[rb][dj][2] * inv);
      o4.w = f2bf(oacc[rb][dj][3] * inv);
      *(short4*)(ctx + row * D_MODEL + h * DHEAD + dj * 16 + q * 4) = o4;
    }
  }
}

// ---------------------------------------------------------------------------
extern "C" void kernel_launch(void* const* d_in, const int* in_sizes, int n_in,
                              void* d_out, int out_size, void* d_ws, size_t ws_size,
                              hipStream_t stream) {
  (void)in_sizes; (void)n_in; (void)out_size; (void)ws_size;

  const float* x  = (const float*)d_in[0];
  const int*   pm = (const int*)  d_in[1];
  const float* Wq = (const float*)d_in[2];
  const float* bq = (const float*)d_in[3];
  const float* Wk = (const float*)d_in[4];
  const float* bk = (const float*)d_in[5];
  const float* Wv = (const float*)d_in[6];
  const float* bv = (const float*)d_in[7];
  const float* Wo = (const float*)d_in[8];
  const float* bo = (const float*)d_in[9];

  const size_t WMAT = (size_t)D_MODEL * D_MODEL;   // 1M elems
  const size_t TOKD = (size_t)M_TOK * D_MODEL;     // 4M elems

  short* base = (short*)d_ws;
  short* Wt = base;              // 4 transposed bf16 weights: 8 MB
  short* xb = base + 4 * WMAT;   // bf16 x: 8 MB
  short* Qw = xb + TOKD;         // 8 MB (z=0, pre-scaled by QSCALE)
  short* Kw = Qw + TOKD;         // 8 MB (z=1)
  short* Vtw = Kw + TOKD;        // 8 MB Vt[b][n][s], masked rows zeroed, key-permuted
  short* Cw = Vtw + TOKD;        // 8 MB  (total 48 MB of ws)

  prep<<<dim3(16, 16, 5), 256, 0, stream>>>(x, xb, Wq, Wk, Wv, Wo, Wt);
  gemm128<false, true, 128><<<dim3(M_TOK / 128, D_MODEL / 128, 3), 256, 0, stream>>>(
      xb, Wt, bq, bk, bv, Qw, Vtw, pm);
  attn_flash<<<dim3(SEQ / 128, NHEAD, BATCH), 512, 0, stream>>>(Qw, Kw, Vtw, pm, Cw);
  gemm128<true, false, 64><<<dim3(M_TOK / 128, D_MODEL / 64, 1), 256, 0, stream>>>(
      Cw, Wt + 3 * WMAT, bo, bo, bo, d_out, nullptr, nullptr);
}